// Round 3
// baseline (17487.247 us; speedup 1.0000x reference)
//
#include <hip/hip_runtime.h>

// ---- workspace layout (float-element offsets), total ~84.4 MB ----
// hbuf   : f32 [2][32][1024]   ping-pong hidden state (256 KB)
// cstate : f32 [32][1024]      cell state             (128 KB)
// bar    : int[32768]          barrier region (128 KB reserved):
//            arrival flags : bar[b*16], b=0..255   (64 B apart)
//            release slots : bar[8192 + l*64], l=0..15
// xpc    : f32 [1024][4096]    x@W chunk (32 steps)   (16 MB)
// states : f32 [16384][1024]   all h_t, row = t*32+b  (64 MB)
#define OFF_H      0ull
#define OFF_C      65536ull
#define OFF_BAR    98304ull
#define OFF_XPC    131072ull
#define OFF_STATES 4325376ull

#define BAR_REL    8192

#define AL(p) __hip_atomic_load((p), __ATOMIC_RELAXED, __HIP_MEMORY_SCOPE_AGENT)
#define AS(p, v) __hip_atomic_store((p), (v), __ATOMIC_RELAXED, __HIP_MEMORY_SCOPE_AGENT)

static __device__ inline float sigmoidf_(float x) { return 1.f / (1.f + __expf(-x)); }
static __device__ inline float tanhf_(float x) { return 1.f - 2.f / (1.f + __expf(2.f * x)); }

// ---------------------------------------------------------------------------
// init: zero hbuf (65536 f32), cstate (32768 f32), bar (16384 ints used).
// ---------------------------------------------------------------------------
__global__ __launch_bounds__(256) void k_init(float* hb, float* cs, int* bar) {
    int i = blockIdx.x * 256 + threadIdx.x;
    hb[i] = 0.f;
    if (i < 32768) cs[i] = 0.f;
    if (i < 16384) bar[i] = 0;
}

// ---------------------------------------------------------------------------
// gemm0 (one 32-step chunk): xpc[Rl][4096] = x[b][t0+(Rl>>5)][:] @ [Wi|Wf|Wg|Wc] + b
// (unchanged, green)
// ---------------------------------------------------------------------------
__global__ __launch_bounds__(256) void k_gemm0(
    const float* __restrict__ x,
    const float* __restrict__ Wi, const float* __restrict__ Wf,
    const float* __restrict__ Wg, const float* __restrict__ Wc,
    const float* __restrict__ bi, const float* __restrict__ bfv,
    const float* __restrict__ bg, const float* __restrict__ bc,
    float* __restrict__ xpc, int t0)
{
    __shared__ float Ash[16 * 128];
    __shared__ float Bsh[16 * 128];
    int tid = threadIdx.x;
    int bm = blockIdx.x >> 5, bn = blockIdx.x & 31;
    int r0 = bm * 128, n0 = bn * 128;
    int gate = bn >> 3;
    int nloc = (bn & 7) * 128;
    const float* W; const float* bias;
    if (gate == 0)      { W = Wi; bias = bi; }
    else if (gate == 1) { W = Wf; bias = bfv; }
    else if (gate == 2) { W = Wg; bias = bg; }
    else                { W = Wc; bias = bc; }

    int mg = tid >> 4, ng = tid & 15;
    int m0 = mg * 8, n0l = ng * 8;
    int sm = tid >> 1, skh = (tid & 1) * 8;
    int sk = tid >> 4, snof = (tid & 15) * 8;
    int Ra = r0 + sm;
    const float* aptr = x + (size_t)(Ra & 31) * 524288
                          + (size_t)(t0 + (Ra >> 5)) * 1024 + skh;

    float acc[8][8];
    for (int i = 0; i < 8; i++)
        for (int j = 0; j < 8; j++) acc[i][j] = 0.f;

    for (int k0 = 0; k0 < 1024; k0 += 16) {
        float4 av0 = *(const float4*)(aptr + k0);
        float4 av1 = *(const float4*)(aptr + k0 + 4);
        float4 bv0 = *(const float4*)(W + (size_t)(k0 + sk) * 1024 + nloc + snof);
        float4 bv1 = *(const float4*)(W + (size_t)(k0 + sk) * 1024 + nloc + snof + 4);
        Ash[(skh + 0) * 128 + sm] = av0.x;
        Ash[(skh + 1) * 128 + sm] = av0.y;
        Ash[(skh + 2) * 128 + sm] = av0.z;
        Ash[(skh + 3) * 128 + sm] = av0.w;
        Ash[(skh + 4) * 128 + sm] = av1.x;
        Ash[(skh + 5) * 128 + sm] = av1.y;
        Ash[(skh + 6) * 128 + sm] = av1.z;
        Ash[(skh + 7) * 128 + sm] = av1.w;
        *(float4*)&Bsh[sk * 128 + snof] = bv0;
        *(float4*)&Bsh[sk * 128 + snof + 4] = bv1;
        __syncthreads();
#pragma unroll
        for (int k = 0; k < 16; k++) {
            float4 a0 = *(const float4*)&Ash[k * 128 + m0];
            float4 a1 = *(const float4*)&Ash[k * 128 + m0 + 4];
            float4 b0 = *(const float4*)&Bsh[k * 128 + n0l];
            float4 b1 = *(const float4*)&Bsh[k * 128 + n0l + 4];
            float aa[8], bb[8];
            aa[0] = a0.x; aa[1] = a0.y; aa[2] = a0.z; aa[3] = a0.w;
            aa[4] = a1.x; aa[5] = a1.y; aa[6] = a1.z; aa[7] = a1.w;
            bb[0] = b0.x; bb[1] = b0.y; bb[2] = b0.z; bb[3] = b0.w;
            bb[4] = b1.x; bb[5] = b1.y; bb[6] = b1.z; bb[7] = b1.w;
#pragma unroll
            for (int i = 0; i < 8; i++)
#pragma unroll
                for (int j = 0; j < 8; j++)
                    acc[i][j] = __builtin_fmaf(aa[i], bb[j], acc[i][j]);
        }
        __syncthreads();
    }
    float fbs[8];
#pragma unroll
    for (int j = 0; j < 8; j++) fbs[j] = bias[nloc + n0l + j];
    for (int i = 0; i < 8; i++) {
        size_t rowoff = (size_t)(r0 + m0 + i) * 4096 + n0 + n0l;
#pragma unroll
        for (int j = 0; j < 8; j++)
            xpc[rowoff + j] = acc[i][j] + fbs[j];
    }
}

// ---------------------------------------------------------------------------
// k_scan32 (REWORKED this round):
//  - wave-major mapping: wave wv = gate, lane ku = k-group; lane's k-set is
//    STRIDED (k = j*256 + ku*4 + i) so LDS fragment reads are a linear bank
//    sweep (conflict-free) and k-reduction is an intra-wave shfl butterfly.
//  - h(t) staged ONCE per step into hsh[32][1024] (128 KB LDS): one LLC
//    latency exposure per step instead of 8.
//  - zbuf eliminated -> 1 block barrier per pass (zfin parity ping-pong).
//  - grid barrier: store-only arrival flags (bar[bid*16]), block 0 detects
//    with 256 parallel loads + __syncthreads_and, then stores 16 release
//    slots. No RMW chains.
//  - XCD column swizzle: col0 = ((bid&7)*32 + (bid>>3))*4 so the 8 blocks
//    sharing each xpc/U cache line are on the SAME XCD (L2 serves 7/8).
// Coherence rules carried over from green R2: h stores = write-through
// RELAXED/AGENT atomics (drained by __syncthreads before flag store);
// h loads = RELAXED/AGENT atomic loads (L2-bypassing).
// ---------------------------------------------------------------------------
__global__ __launch_bounds__(256, 1) void k_scan32(
    const float* __restrict__ Ui, const float* __restrict__ Uf,
    const float* __restrict__ Ug, const float* __restrict__ Uc,
    const float* __restrict__ xpc,
    float* hbuf, float* cstate, float* states, int* bar, int t0)
{
    __shared__ float hsh[32 * 1024];   // 128 KB  [b(32)][k(1024)]
    __shared__ float zfin[2][64];      // parity ping-pong [b*16 + g*4 + c]
    __shared__ float csh[16 * 8];      // c-state: [owner(16)][pass(8)]
    int tid = threadIdx.x;
    int wv = tid >> 6;                 // wave = gate
    int ku = tid & 63;                 // lane = k-group
    int col0 = (((blockIdx.x & 7) << 5) | (blockIdx.x >> 3)) << 2;  // XCD swizzle
    const float* Bu;
    if (wv == 0) Bu = Ui; else if (wv == 1) Bu = Uf;
    else if (wv == 2) Bu = Ug; else Bu = Uc;

    // persistent U slice, strided k: ur[j*4+i] = U[j*256+ku*4+i][col0..col0+3]
    float4 ur[16];
#pragma unroll
    for (int j = 0; j < 4; j++)
#pragma unroll
        for (int i = 0; i < 4; i++)
            ur[j * 4 + i] = *(const float4*)(Bu + (size_t)(j * 256 + ku * 4 + i) * 1024 + col0);

    int ob = tid >> 2, oc = tid & 3;   // owner roles (tid < 16)
    if (tid < 16) {
        for (int p = 0; p < 8; p++)
            csh[tid * 8 + p] = cstate[(size_t)(p * 4 + ob) * 1024 + col0 + oc];
    }
    __syncthreads();

    for (int tt = 0; tt < 32; tt++) {
        int t = t0 + tt;
        const float* hb = hbuf + (size_t)(t & 1) * 32768;
        float* hn = hbuf + (size_t)((t + 1) & 1) * 32768;

        // ---- stage ALL of h(t): 32768 f32, 128 coherent dwords/thread ----
#pragma unroll 4
        for (int q = 0; q < 32; q++) {
            int f = tid + q * 256;
            int r = f >> 8, k4 = f & 255;
            const float* src = hb + (size_t)r * 1024 + k4 * 4;
            float4 hv4;
            hv4.x = AL(src + 0);
            hv4.y = AL(src + 1);
            hv4.z = AL(src + 2);
            hv4.w = AL(src + 3);
            *(float4*)&hsh[r * 1024 + k4 * 4] = hv4;
        }
        __syncthreads();

        for (int p = 0; p < 8; p++) {
            // owners: fetch xp for this pass early (hidden behind FMA+butterfly)
            float xg0 = 0.f, xg1 = 0.f, xg2 = 0.f, xg3 = 0.f;
            if (tid < 16) {
                const float* xr = xpc + (size_t)(tt * 32 + p * 4 + ob) * 4096 + col0 + oc;
                xg0 = xr[0];
                xg1 = xr[1024];
                xg2 = xr[2048];
                xg3 = xr[3072];
            }

            float acc[4][4];
            for (int b = 0; b < 4; b++)
                for (int c = 0; c < 4; c++) acc[b][c] = 0.f;
#pragma unroll
            for (int b = 0; b < 4; b++) {
#pragma unroll
                for (int j = 0; j < 4; j++) {
                    float4 hv = *(const float4*)&hsh[(p * 4 + b) * 1024 + j * 256 + ku * 4];
                    float4 u0 = ur[j * 4 + 0];
                    float4 u1 = ur[j * 4 + 1];
                    float4 u2 = ur[j * 4 + 2];
                    float4 u3 = ur[j * 4 + 3];
                    acc[b][0] = __builtin_fmaf(hv.x, u0.x, acc[b][0]);
                    acc[b][1] = __builtin_fmaf(hv.x, u0.y, acc[b][1]);
                    acc[b][2] = __builtin_fmaf(hv.x, u0.z, acc[b][2]);
                    acc[b][3] = __builtin_fmaf(hv.x, u0.w, acc[b][3]);
                    acc[b][0] = __builtin_fmaf(hv.y, u1.x, acc[b][0]);
                    acc[b][1] = __builtin_fmaf(hv.y, u1.y, acc[b][1]);
                    acc[b][2] = __builtin_fmaf(hv.y, u1.z, acc[b][2]);
                    acc[b][3] = __builtin_fmaf(hv.y, u1.w, acc[b][3]);
                    acc[b][0] = __builtin_fmaf(hv.z, u2.x, acc[b][0]);
                    acc[b][1] = __builtin_fmaf(hv.z, u2.y, acc[b][1]);
                    acc[b][2] = __builtin_fmaf(hv.z, u2.z, acc[b][2]);
                    acc[b][3] = __builtin_fmaf(hv.z, u2.w, acc[b][3]);
                    acc[b][0] = __builtin_fmaf(hv.w, u3.x, acc[b][0]);
                    acc[b][1] = __builtin_fmaf(hv.w, u3.y, acc[b][1]);
                    acc[b][2] = __builtin_fmaf(hv.w, u3.z, acc[b][2]);
                    acc[b][3] = __builtin_fmaf(hv.w, u3.w, acc[b][3]);
                }
            }

            // intra-wave k-reduction: 6-step butterfly (each wave = one gate)
#pragma unroll
            for (int b = 0; b < 4; b++)
#pragma unroll
                for (int c = 0; c < 4; c++) {
                    float v = acc[b][c];
                    v += __shfl_xor(v, 1, 64);
                    v += __shfl_xor(v, 2, 64);
                    v += __shfl_xor(v, 4, 64);
                    v += __shfl_xor(v, 8, 64);
                    v += __shfl_xor(v, 16, 64);
                    v += __shfl_xor(v, 32, 64);
                    acc[b][c] = v;
                }
            // lane ku<16 publishes (b=ku>>2, c=ku&3) for its gate wv
            if (ku < 16)
                zfin[p & 1][(ku >> 2) * 16 + wv * 4 + (ku & 3)] = acc[ku >> 2][ku & 3];
            __syncthreads();

            // gate math: 16 owners (wave 0), one (b=p*4+ob, col=col0+oc) each
            if (tid < 16) {
                int b = p * 4 + ob;
                float zi = zfin[p & 1][ob * 16 + 0 * 4 + oc] + xg0;
                float zf = zfin[p & 1][ob * 16 + 1 * 4 + oc] + xg1;
                float zg = zfin[p & 1][ob * 16 + 2 * 4 + oc] + xg2;
                float zc = zfin[p & 1][ob * 16 + 3 * 4 + oc] + xg3;
                float ig = sigmoidf_(zi);
                float fg = sigmoidf_(zf);
                float gg = sigmoidf_(zg);   // reference applies sigmoid to g
                float ct = tanhf_(zc);
                float cv = fg * csh[tid * 8 + p] + ig * ct;
                csh[tid * 8 + p] = cv;
                float hv = gg * tanhf_(cv);
                AS(&hn[(size_t)b * 1024 + col0 + oc], hv);   // write-through
                states[((size_t)t * 32 + b) * 1024 + col0 + oc] = hv;
            }
            // no trailing sync: next pass uses other zfin parity; hsh is RO
        }

        // ---- grid barrier: store-flag arrival, block-0 parallel detector ----
        __syncthreads();                     // drains owners' h write-throughs
        if (blockIdx.x == 0) {
            for (;;) {
                int ok = 1;
                if (tid != 0) ok = (AL(&bar[tid * 16]) > t);
                if (__syncthreads_and(ok)) break;
                __builtin_amdgcn_s_sleep(1);
            }
            if (tid < 16)
                AS(&bar[BAR_REL + tid * 64], t + 1);
        } else {
            if (tid == 0) {
                AS(&bar[blockIdx.x * 16], t + 1);
                while (AL(&bar[BAR_REL + (blockIdx.x & 15) * 64]) <= t)
                    __builtin_amdgcn_s_sleep(2);
            }
            __syncthreads();
        }
    }

    // persist c-state for the next chunk launch (plain; kernel-end flush)
    if (tid < 16) {
        for (int p = 0; p < 8; p++)
            cstate[(size_t)(p * 4 + ob) * 1024 + col0 + oc] = csh[tid * 8 + p];
    }
}

// ---------------------------------------------------------------------------
// gemm1: out[b][t][:] = relu(states[t*32+b][:] @ Wo + bo)  (unchanged, green)
// ---------------------------------------------------------------------------
__global__ __launch_bounds__(256) void k_gemm1(
    const float* __restrict__ A, const float* __restrict__ Wo,
    const float* __restrict__ bo, float* __restrict__ outp)
{
    __shared__ float Ash[16 * 128];
    __shared__ float Bsh[16 * 128];
    int tid = threadIdx.x;
    int bm = blockIdx.x >> 3, bn = blockIdx.x & 7;
    int r0 = bm * 128, n0 = bn * 128;
    int mg = tid >> 4, ng = tid & 15;
    int m0 = mg * 8, n0l = ng * 8;
    int sm = tid >> 1, skh = (tid & 1) * 8;
    int sk = tid >> 4, snof = (tid & 15) * 8;
    const float* aptr = A + (size_t)(r0 + sm) * 1024 + skh;

    float acc[8][8];
    for (int i = 0; i < 8; i++)
        for (int j = 0; j < 8; j++) acc[i][j] = 0.f;

    for (int k0 = 0; k0 < 1024; k0 += 16) {
        float4 av0 = *(const float4*)(aptr + k0);
        float4 av1 = *(const float4*)(aptr + k0 + 4);
        float4 bv0 = *(const float4*)(Wo + (size_t)(k0 + sk) * 1024 + n0 + snof);
        float4 bv1 = *(const float4*)(Wo + (size_t)(k0 + sk) * 1024 + n0 + snof + 4);
        Ash[(skh + 0) * 128 + sm] = av0.x;
        Ash[(skh + 1) * 128 + sm] = av0.y;
        Ash[(skh + 2) * 128 + sm] = av0.z;
        Ash[(skh + 3) * 128 + sm] = av0.w;
        Ash[(skh + 4) * 128 + sm] = av1.x;
        Ash[(skh + 5) * 128 + sm] = av1.y;
        Ash[(skh + 6) * 128 + sm] = av1.z;
        Ash[(skh + 7) * 128 + sm] = av1.w;
        *(float4*)&Bsh[sk * 128 + snof] = bv0;
        *(float4*)&Bsh[sk * 128 + snof + 4] = bv1;
        __syncthreads();
#pragma unroll
        for (int k = 0; k < 16; k++) {
            float4 a0 = *(const float4*)&Ash[k * 128 + m0];
            float4 a1 = *(const float4*)&Ash[k * 128 + m0 + 4];
            float4 b0 = *(const float4*)&Bsh[k * 128 + n0l];
            float4 b1 = *(const float4*)&Bsh[k * 128 + n0l + 4];
            float aa[8], bb[8];
            aa[0] = a0.x; aa[1] = a0.y; aa[2] = a0.z; aa[3] = a0.w;
            aa[4] = a1.x; aa[5] = a1.y; aa[6] = a1.z; aa[7] = a1.w;
            bb[0] = b0.x; bb[1] = b0.y; bb[2] = b0.z; bb[3] = b0.w;
            bb[4] = b1.x; bb[5] = b1.y; bb[6] = b1.z; bb[7] = b1.w;
#pragma unroll
            for (int i = 0; i < 8; i++)
#pragma unroll
                for (int j = 0; j < 8; j++)
                    acc[i][j] = __builtin_fmaf(aa[i], bb[j], acc[i][j]);
        }
        __syncthreads();
    }
    float fbs[8];
#pragma unroll
    for (int j = 0; j < 8; j++) fbs[j] = bo[n0 + n0l + j];
    for (int i = 0; i < 8; i++) {
        int R = r0 + m0 + i;
        size_t rowoff = (size_t)(R & 31) * 524288 + (size_t)(R >> 5) * 1024 + n0 + n0l;
#pragma unroll
        for (int j = 0; j < 8; j++) {
            float v = acc[i][j] + fbs[j];
            outp[rowoff + j] = v > 0.f ? v : 0.f;
        }
    }
}

extern "C" void kernel_launch(void* const* d_in, const int* in_sizes, int n_in,
                              void* d_out, int out_size, void* d_ws, size_t ws_size,
                              hipStream_t stream)
{
    const float* x   = (const float*)d_in[0];
    const float* Wi  = (const float*)d_in[1];
    const float* Ui  = (const float*)d_in[2];
    const float* Wf  = (const float*)d_in[3];
    const float* Uf  = (const float*)d_in[4];
    const float* Wg  = (const float*)d_in[5];
    const float* Ug  = (const float*)d_in[6];
    const float* Wc  = (const float*)d_in[7];
    const float* Uc  = (const float*)d_in[8];
    const float* Wo  = (const float*)d_in[9];
    const float* bi  = (const float*)d_in[10];
    const float* bfv = (const float*)d_in[11];
    const float* bg  = (const float*)d_in[12];
    const float* bc  = (const float*)d_in[13];
    const float* bo  = (const float*)d_in[14];

    float* ws     = (float*)d_ws;
    float* hbuf   = ws + OFF_H;
    float* cstate = ws + OFF_C;
    int*   bar    = (int*)(ws + OFF_BAR);
    float* xpc    = ws + OFF_XPC;
    float* states = ws + OFF_STATES;
    float* outp   = (float*)d_out;

    k_init<<<256, 256, 0, stream>>>(hbuf, cstate, bar);
    for (int c = 0; c < 16; c++) {
        k_gemm0<<<256, 256, 0, stream>>>(x, Wi, Wf, Wg, Wc, bi, bfv, bg, bc,
                                         xpc, c * 32);
        k_scan32<<<256, 256, 0, stream>>>(Ui, Uf, Ug, Uc, xpc,
                                          hbuf, cstate, states, bar, c * 32);
    }
    k_gemm1<<<1024, 256, 0, stream>>>(states, Wo, bo, outp);
}

// Round 4
// 13641.852 us; speedup vs baseline: 1.2819x; 1.2819x over previous
//
#include <hip/hip_runtime.h>

// ---- workspace layout (float-element offsets), total ~84.4 MB ----
// hbuf   : f32 [2][32][1024]   ping-pong hidden state (256 KB)
// cstate : f32 [32][1024]      cell state             (128 KB)
// bar    : int[32768]          sync region (128 KB reserved):
//            prog[b]  : bar[b*16], b=0..255      (64 B apart, monotone)
//            gminrep  : bar[8192 + l*64], l=0..15 (replicated global min)
// xpc    : f32 [1024][4096]    x@W chunk (32 steps)   (16 MB)
// states : f32 [16384][1024]   all h_t, row = t*32+b  (64 MB)
#define OFF_H      0ull
#define OFF_C      65536ull
#define OFF_BAR    98304ull
#define OFF_XPC    131072ull
#define OFF_STATES 4325376ull

#define BAR_REL    8192

#define AL(p) __hip_atomic_load((p), __ATOMIC_RELAXED, __HIP_MEMORY_SCOPE_AGENT)
#define AS(p, v) __hip_atomic_store((p), (v), __ATOMIC_RELAXED, __HIP_MEMORY_SCOPE_AGENT)

static __device__ inline float sigmoidf_(float x) { return 1.f / (1.f + __expf(-x)); }
static __device__ inline float tanhf_(float x) { return 1.f - 2.f / (1.f + __expf(2.f * x)); }

// raw barrier: drain LDS writes only; global loads/stores stay in flight
#define BARRIER_LDS()                                          \
    asm volatile("s_waitcnt lgkmcnt(0)" ::: "memory");         \
    __builtin_amdgcn_s_barrier();                              \
    __builtin_amdgcn_sched_barrier(0);

// ---------------------------------------------------------------------------
// init: zero hbuf (65536 f32), cstate (32768 f32), bar (16384 ints used).
// ---------------------------------------------------------------------------
__global__ __launch_bounds__(256) void k_init(float* hb, float* cs, int* bar) {
    int i = blockIdx.x * 256 + threadIdx.x;
    hb[i] = 0.f;
    if (i < 32768) cs[i] = 0.f;
    if (i < 16384) bar[i] = 0;
}

// ---------------------------------------------------------------------------
// gemm0 (one 32-step chunk): xpc[Rl][4096] = x[b][t0+(Rl>>5)][:] @ [Wi|Wf|Wg|Wc] + b
// (unchanged, green)
// ---------------------------------------------------------------------------
__global__ __launch_bounds__(256) void k_gemm0(
    const float* __restrict__ x,
    const float* __restrict__ Wi, const float* __restrict__ Wf,
    const float* __restrict__ Wg, const float* __restrict__ Wc,
    const float* __restrict__ bi, const float* __restrict__ bfv,
    const float* __restrict__ bg, const float* __restrict__ bc,
    float* __restrict__ xpc, int t0)
{
    __shared__ float Ash[16 * 128];
    __shared__ float Bsh[16 * 128];
    int tid = threadIdx.x;
    int bm = blockIdx.x >> 5, bn = blockIdx.x & 31;
    int r0 = bm * 128, n0 = bn * 128;
    int gate = bn >> 3;
    int nloc = (bn & 7) * 128;
    const float* W; const float* bias;
    if (gate == 0)      { W = Wi; bias = bi; }
    else if (gate == 1) { W = Wf; bias = bfv; }
    else if (gate == 2) { W = Wg; bias = bg; }
    else                { W = Wc; bias = bc; }

    int mg = tid >> 4, ng = tid & 15;
    int m0 = mg * 8, n0l = ng * 8;
    int sm = tid >> 1, skh = (tid & 1) * 8;
    int sk = tid >> 4, snof = (tid & 15) * 8;
    int Ra = r0 + sm;
    const float* aptr = x + (size_t)(Ra & 31) * 524288
                          + (size_t)(t0 + (Ra >> 5)) * 1024 + skh;

    float acc[8][8];
    for (int i = 0; i < 8; i++)
        for (int j = 0; j < 8; j++) acc[i][j] = 0.f;

    for (int k0 = 0; k0 < 1024; k0 += 16) {
        float4 av0 = *(const float4*)(aptr + k0);
        float4 av1 = *(const float4*)(aptr + k0 + 4);
        float4 bv0 = *(const float4*)(W + (size_t)(k0 + sk) * 1024 + nloc + snof);
        float4 bv1 = *(const float4*)(W + (size_t)(k0 + sk) * 1024 + nloc + snof + 4);
        Ash[(skh + 0) * 128 + sm] = av0.x;
        Ash[(skh + 1) * 128 + sm] = av0.y;
        Ash[(skh + 2) * 128 + sm] = av0.z;
        Ash[(skh + 3) * 128 + sm] = av0.w;
        Ash[(skh + 4) * 128 + sm] = av1.x;
        Ash[(skh + 5) * 128 + sm] = av1.y;
        Ash[(skh + 6) * 128 + sm] = av1.z;
        Ash[(skh + 7) * 128 + sm] = av1.w;
        *(float4*)&Bsh[sk * 128 + snof] = bv0;
        *(float4*)&Bsh[sk * 128 + snof + 4] = bv1;
        __syncthreads();
#pragma unroll
        for (int k = 0; k < 16; k++) {
            float4 a0 = *(const float4*)&Ash[k * 128 + m0];
            float4 a1 = *(const float4*)&Ash[k * 128 + m0 + 4];
            float4 b0 = *(const float4*)&Bsh[k * 128 + n0l];
            float4 b1 = *(const float4*)&Bsh[k * 128 + n0l + 4];
            float aa[8], bb[8];
            aa[0] = a0.x; aa[1] = a0.y; aa[2] = a0.z; aa[3] = a0.w;
            aa[4] = a1.x; aa[5] = a1.y; aa[6] = a1.z; aa[7] = a1.w;
            bb[0] = b0.x; bb[1] = b0.y; bb[2] = b0.z; bb[3] = b0.w;
            bb[4] = b1.x; bb[5] = b1.y; bb[6] = b1.z; bb[7] = b1.w;
#pragma unroll
            for (int i = 0; i < 8; i++)
#pragma unroll
                for (int j = 0; j < 8; j++)
                    acc[i][j] = __builtin_fmaf(aa[i], bb[j], acc[i][j]);
        }
        __syncthreads();
    }
    float fbs[8];
#pragma unroll
    for (int j = 0; j < 8; j++) fbs[j] = bias[nloc + n0l + j];
    for (int i = 0; i < 8; i++) {
        size_t rowoff = (size_t)(r0 + m0 + i) * 4096 + n0 + n0l;
#pragma unroll
        for (int j = 0; j < 8; j++)
            xpc[rowoff + j] = acc[i][j] + fbs[j];
    }
}

// ---------------------------------------------------------------------------
// k_scan32 (PIPELINED REWORK):
// 256 worker blocks (4 h-cols each, XCD-swizzled) + 1 sequencer block.
// NO grid barrier. Pass-level producer/consumer flow control:
//  - pass Q = tt*8+p computes batches 4p..4p+3 of step t0+tt.
//  - wave0 owners store h (write-through), wait own vmcnt(0), publish
//    prog[bid] = t0*8+Q+1 (relaxed store; no fences anywhere).
//  - sequencer block (bid 256, 1 wave) loops: min over 256 prog -> 16
//    replicated gmin lines.
//  - staging (waves 1-3 only) for pass Q is gated on gmin >= t0*8+Q-7
//    (checked against a 1-pass-stale cached value; zero cost steady-state).
//    Max block lead <= ~8 passes < 16-pass buffer reuse distance => safe.
//  - raw s_barrier + lgkmcnt(0) only (2 per pass): global loads/stores stay
//    in flight across barriers (no vmcnt(0) drain) => 2-pass-deep register
//    prefetch of h actually pipelines.
//  - k-reduce: merged shfl butterfly, 17 shfls for 16 values (was 96).
// ---------------------------------------------------------------------------
__global__ __launch_bounds__(256, 1) void k_scan32(
    const float* __restrict__ Ui, const float* __restrict__ Uf,
    const float* __restrict__ Ug, const float* __restrict__ Uc,
    const float* __restrict__ xpc,
    float* hbuf, float* cstate, float* states, int* bar, int t0)
{
    int tid = threadIdx.x;

    // ---- sequencer block ----
    if (blockIdx.x == 256) {
        if (tid < 64) {
            int endv = (t0 + 32) * 8;
            for (;;) {
                int m0 = AL(&bar[(tid * 4 + 0) * 16]);
                int m1 = AL(&bar[(tid * 4 + 1) * 16]);
                int m2 = AL(&bar[(tid * 4 + 2) * 16]);
                int m3 = AL(&bar[(tid * 4 + 3) * 16]);
                int m = min(min(m0, m1), min(m2, m3));
                m = min(m, __shfl_xor(m, 1, 64));
                m = min(m, __shfl_xor(m, 2, 64));
                m = min(m, __shfl_xor(m, 4, 64));
                m = min(m, __shfl_xor(m, 8, 64));
                m = min(m, __shfl_xor(m, 16, 64));
                m = min(m, __shfl_xor(m, 32, 64));
                if (tid < 16) AS(&bar[BAR_REL + tid * 64], m);
                if (m >= endv) break;
            }
        }
        return;
    }

    __shared__ float hsh[2][4][1024];  // 32 KB double-buffered pass tile
    __shared__ float zfin[2][64];      // parity ping-pong [b*16 + g*4 + c]
    __shared__ float csh[16 * 8];      // c-state: [owner(16)][pass(8)]

    int wv = tid >> 6;                 // wave = gate
    int ku = tid & 63;                 // lane = k-group
    int col0 = (((blockIdx.x & 7) << 5) | (blockIdx.x >> 3)) << 2;  // XCD swizzle
    const float* Bu;
    if (wv == 0) Bu = Ui; else if (wv == 1) Bu = Uf;
    else if (wv == 2) Bu = Ug; else Bu = Uc;

    // persistent U slice, strided k: ur[j*4+i] = U[j*256+ku*4+i][col0..col0+3]
    float4 ur[16];
#pragma unroll
    for (int j = 0; j < 4; j++)
#pragma unroll
        for (int i = 0; i < 4; i++)
            ur[j * 4 + i] = *(const float4*)(Bu + (size_t)(j * 256 + ku * 4 + i) * 1024 + col0);

    int ob = tid >> 2, oc = tid & 3;   // owner roles (tid < 16)
    if (tid < 16) {
        for (int p = 0; p < 8; p++)
            csh[tid * 8 + p] = cstate[(size_t)(p * 4 + ob) * 1024 + col0 + oc];
    }

    int* gml = &bar[BAR_REL + (blockIdx.x & 15) * 64];
    int gv = 0;
    if (tid >= 64) gv = AL(gml);
    float4 gA[6], gB[6];

#define NEED(Q) (t0 * 8 + (Q) - 7)

#define STAGE(g, Q)                                                           \
    if (tid >= 64) {                                                          \
        if (gv < NEED(Q)) {                                                   \
            do { gv = AL(gml); if (gv >= NEED(Q)) break;                      \
                 __builtin_amdgcn_s_sleep(1); } while (1);                    \
        }                                                                     \
        asm volatile("" ::: "memory");                                        \
        const float* hb_ = hbuf + (size_t)(((Q) >> 3) & 1) * 32768            \
                         + (size_t)(((Q) & 7) * 4) * 1024;                    \
        _Pragma("unroll")                                                     \
        for (int q = 0; q < 6; q++) {                                         \
            int idx = (tid - 64) + q * 192;                                   \
            if (idx < 1024) {                                                 \
                const float* s_ = hb_ + (size_t)(idx >> 8) * 1024 + (idx & 255) * 4; \
                g[q].x = AL(s_ + 0);                                          \
                g[q].y = AL(s_ + 1);                                          \
                g[q].z = AL(s_ + 2);                                          \
                g[q].w = AL(s_ + 3);                                          \
            }                                                                 \
        }                                                                     \
        gv = AL(gml);  /* refresh for next check; waited at next use */       \
    }

#define COMMIT(g, Q)                                                          \
    if (tid >= 64) {                                                          \
        float* dst_ = &hsh[(Q) & 1][0][0];                                    \
        _Pragma("unroll")                                                     \
        for (int q = 0; q < 6; q++) {                                         \
            int idx = (tid - 64) + q * 192;                                   \
            if (idx < 1024) *(float4*)(dst_ + idx * 4) = g[q];                \
        }                                                                     \
    }

#define PASS(Q)                                                               \
    {                                                                         \
        int t_ = t0 + ((Q) >> 3), p_ = (Q) & 7;                               \
        float xg0 = 0.f, xg1 = 0.f, xg2 = 0.f, xg3 = 0.f;                     \
        if (tid < 16) {                                                       \
            const float* xr = xpc + (size_t)((((Q) >> 3) * 32) + p_ * 4 + ob) * 4096 + col0 + oc; \
            xg0 = xr[0]; xg1 = xr[1024]; xg2 = xr[2048]; xg3 = xr[3072];      \
        }                                                                     \
        float w_[16];                                                         \
        {                                                                     \
            const float* hrow = &hsh[(Q) & 1][0][0];                          \
            _Pragma("unroll")                                                 \
            for (int b = 0; b < 4; b++) {                                     \
                float a0 = 0.f, a1 = 0.f, a2 = 0.f, a3 = 0.f;                 \
                _Pragma("unroll")                                             \
                for (int j = 0; j < 4; j++) {                                 \
                    float4 hv = *(const float4*)(hrow + b * 1024 + j * 256 + ku * 4); \
                    float4 u0 = ur[j * 4 + 0];                                \
                    float4 u1 = ur[j * 4 + 1];                                \
                    float4 u2 = ur[j * 4 + 2];                                \
                    float4 u3 = ur[j * 4 + 3];                                \
                    a0 = __builtin_fmaf(hv.x, u0.x, a0);                      \
                    a1 = __builtin_fmaf(hv.x, u0.y, a1);                      \
                    a2 = __builtin_fmaf(hv.x, u0.z, a2);                      \
                    a3 = __builtin_fmaf(hv.x, u0.w, a3);                      \
                    a0 = __builtin_fmaf(hv.y, u1.x, a0);                      \
                    a1 = __builtin_fmaf(hv.y, u1.y, a1);                      \
                    a2 = __builtin_fmaf(hv.y, u1.z, a2);                      \
                    a3 = __builtin_fmaf(hv.y, u1.w, a3);                      \
                    a0 = __builtin_fmaf(hv.z, u2.x, a0);                      \
                    a1 = __builtin_fmaf(hv.z, u2.y, a1);                      \
                    a2 = __builtin_fmaf(hv.z, u2.z, a2);                      \
                    a3 = __builtin_fmaf(hv.z, u2.w, a3);                      \
                    a0 = __builtin_fmaf(hv.w, u3.x, a0);                      \
                    a1 = __builtin_fmaf(hv.w, u3.y, a1);                      \
                    a2 = __builtin_fmaf(hv.w, u3.z, a2);                      \
                    a3 = __builtin_fmaf(hv.w, u3.w, a3);                      \
                }                                                             \
                w_[b * 4 + 0] = a0; w_[b * 4 + 1] = a1;                       \
                w_[b * 4 + 2] = a2; w_[b * 4 + 3] = a3;                       \
            }                                                                 \
        }                                                                     \
        /* merged butterfly: index bit k <- lane bit k; lane l ends with S[l&15] */ \
        float u_[8];                                                          \
        _Pragma("unroll")                                                     \
        for (int i = 0; i < 8; i++) {                                         \
            float a = w_[2 * i], b = w_[2 * i + 1];                           \
            float x = (ku & 1) ? a : b;                                       \
            float y = __shfl_xor(x, 1, 64);                                   \
            u_[i] = ((ku & 1) ? b : a) + y;                                   \
        }                                                                     \
        float v_[4];                                                          \
        _Pragma("unroll")                                                     \
        for (int i = 0; i < 4; i++) {                                         \
            float a = u_[2 * i], b = u_[2 * i + 1];                           \
            float x = (ku & 2) ? a : b;                                       \
            float y = __shfl_xor(x, 2, 64);                                   \
            v_[i] = ((ku & 2) ? b : a) + y;                                   \
        }                                                                     \
        float s_[2];                                                          \
        _Pragma("unroll")                                                     \
        for (int i = 0; i < 2; i++) {                                         \
            float a = v_[2 * i], b = v_[2 * i + 1];                           \
            float x = (ku & 4) ? a : b;                                       \
            float y = __shfl_xor(x, 4, 64);                                   \
            s_[i] = ((ku & 4) ? b : a) + y;                                   \
        }                                                                     \
        float r_;                                                             \
        {                                                                     \
            float a = s_[0], b = s_[1];                                       \
            float x = (ku & 8) ? a : b;                                       \
            float y = __shfl_xor(x, 8, 64);                                   \
            r_ = ((ku & 8) ? b : a) + y;                                      \
        }                                                                     \
        r_ += __shfl_xor(r_, 16, 64);                                         \
        r_ += __shfl_xor(r_, 32, 64);                                         \
        if (ku < 16)                                                          \
            zfin[(Q) & 1][(ku >> 2) * 16 + wv * 4 + (ku & 3)] = r_;           \
        BARRIER_LDS();                                                        \
        if (tid < 16) {                                                       \
            int b_ = p_ * 4 + ob;                                             \
            float zi = zfin[(Q) & 1][ob * 16 + 0 + oc] + xg0;                 \
            float zf = zfin[(Q) & 1][ob * 16 + 4 + oc] + xg1;                 \
            float zg = zfin[(Q) & 1][ob * 16 + 8 + oc] + xg2;                 \
            float zc = zfin[(Q) & 1][ob * 16 + 12 + oc] + xg3;                \
            float ig = sigmoidf_(zi);                                         \
            float fg = sigmoidf_(zf);                                         \
            float gg = sigmoidf_(zg);                                         \
            float ct = tanhf_(zc);                                            \
            float cv = fg * csh[tid * 8 + p_] + ig * ct;                      \
            csh[tid * 8 + p_] = cv;                                           \
            float hv = gg * tanhf_(cv);                                       \
            AS(&hbuf[(size_t)((t_ + 1) & 1) * 32768 + (size_t)b_ * 1024 + col0 + oc], hv); \
            states[((size_t)t_ * 32 + b_) * 1024 + col0 + oc] = hv;           \
        }                                                                     \
        if (tid == 0) {                                                       \
            asm volatile("s_waitcnt vmcnt(0)" ::: "memory");                  \
            AS(&bar[blockIdx.x * 16], t0 * 8 + (Q) + 1);                      \
        }                                                                     \
    }

    // prologue: stage passes 0 and 1 (gated on stale gmin from prior chunk)
    { STAGE(gA, 0) }
    { STAGE(gB, 1) }

#pragma unroll 1
    for (int Q = 0; Q < 256; Q += 2) {
        COMMIT(gA, Q)
        BARRIER_LDS();
        if (Q + 2 < 256) { STAGE(gA, Q + 2) }
        PASS(Q)
        COMMIT(gB, Q + 1)
        BARRIER_LDS();
        if (Q + 3 < 256) { STAGE(gB, Q + 3) }
        PASS(Q + 1)
    }

    // persist c-state for the next chunk launch (plain; kernel-end flush)
    if (tid < 16) {
        for (int p = 0; p < 8; p++)
            cstate[(size_t)(p * 4 + ob) * 1024 + col0 + oc] = csh[tid * 8 + p];
    }
#undef NEED
#undef STAGE
#undef COMMIT
#undef PASS
}

// ---------------------------------------------------------------------------
// gemm1: out[b][t][:] = relu(states[t*32+b][:] @ Wo + bo)  (unchanged, green)
// ---------------------------------------------------------------------------
__global__ __launch_bounds__(256) void k_gemm1(
    const float* __restrict__ A, const float* __restrict__ Wo,
    const float* __restrict__ bo, float* __restrict__ outp)
{
    __shared__ float Ash[16 * 128];
    __shared__ float Bsh[16 * 128];
    int tid = threadIdx.x;
    int bm = blockIdx.x >> 3, bn = blockIdx.x & 7;
    int r0 = bm * 128, n0 = bn * 128;
    int mg = tid >> 4, ng = tid & 15;
    int m0 = mg * 8, n0l = ng * 8;
    int sm = tid >> 1, skh = (tid & 1) * 8;
    int sk = tid >> 4, snof = (tid & 15) * 8;
    const float* aptr = A + (size_t)(r0 + sm) * 1024 + skh;

    float acc[8][8];
    for (int i = 0; i < 8; i++)
        for (int j = 0; j < 8; j++) acc[i][j] = 0.f;

    for (int k0 = 0; k0 < 1024; k0 += 16) {
        float4 av0 = *(const float4*)(aptr + k0);
        float4 av1 = *(const float4*)(aptr + k0 + 4);
        float4 bv0 = *(const float4*)(Wo + (size_t)(k0 + sk) * 1024 + n0 + snof);
        float4 bv1 = *(const float4*)(Wo + (size_t)(k0 + sk) * 1024 + n0 + snof + 4);
        Ash[(skh + 0) * 128 + sm] = av0.x;
        Ash[(skh + 1) * 128 + sm] = av0.y;
        Ash[(skh + 2) * 128 + sm] = av0.z;
        Ash[(skh + 3) * 128 + sm] = av0.w;
        Ash[(skh + 4) * 128 + sm] = av1.x;
        Ash[(skh + 5) * 128 + sm] = av1.y;
        Ash[(skh + 6) * 128 + sm] = av1.z;
        Ash[(skh + 7) * 128 + sm] = av1.w;
        *(float4*)&Bsh[sk * 128 + snof] = bv0;
        *(float4*)&Bsh[sk * 128 + snof + 4] = bv1;
        __syncthreads();
#pragma unroll
        for (int k = 0; k < 16; k++) {
            float4 a0 = *(const float4*)&Ash[k * 128 + m0];
            float4 a1 = *(const float4*)&Ash[k * 128 + m0 + 4];
            float4 b0 = *(const float4*)&Bsh[k * 128 + n0l];
            float4 b1 = *(const float4*)&Bsh[k * 128 + n0l + 4];
            float aa[8], bb[8];
            aa[0] = a0.x; aa[1] = a0.y; aa[2] = a0.z; aa[3] = a0.w;
            aa[4] = a1.x; aa[5] = a1.y; aa[6] = a1.z; aa[7] = a1.w;
            bb[0] = b0.x; bb[1] = b0.y; bb[2] = b0.z; bb[3] = b0.w;
            bb[4] = b1.x; bb[5] = b1.y; bb[6] = b1.z; bb[7] = b1.w;
#pragma unroll
            for (int i = 0; i < 8; i++)
#pragma unroll
                for (int j = 0; j < 8; j++)
                    acc[i][j] = __builtin_fmaf(aa[i], bb[j], acc[i][j]);
        }
        __syncthreads();
    }
    float fbs[8];
#pragma unroll
    for (int j = 0; j < 8; j++) fbs[j] = bo[n0 + n0l + j];
    for (int i = 0; i < 8; i++) {
        int R = r0 + m0 + i;
        size_t rowoff = (size_t)(R & 31) * 524288 + (size_t)(R >> 5) * 1024 + n0 + n0l;
#pragma unroll
        for (int j = 0; j < 8; j++) {
            float v = acc[i][j] + fbs[j];
            outp[rowoff + j] = v > 0.f ? v : 0.f;
        }
    }
}

extern "C" void kernel_launch(void* const* d_in, const int* in_sizes, int n_in,
                              void* d_out, int out_size, void* d_ws, size_t ws_size,
                              hipStream_t stream)
{
    const float* x   = (const float*)d_in[0];
    const float* Wi  = (const float*)d_in[1];
    const float* Ui  = (const float*)d_in[2];
    const float* Wf  = (const float*)d_in[3];
    const float* Uf  = (const float*)d_in[4];
    const float* Wg  = (const float*)d_in[5];
    const float* Ug  = (const float*)d_in[6];
    const float* Wc  = (const float*)d_in[7];
    const float* Uc  = (const float*)d_in[8];
    const float* Wo  = (const float*)d_in[9];
    const float* bi  = (const float*)d_in[10];
    const float* bfv = (const float*)d_in[11];
    const float* bg  = (const float*)d_in[12];
    const float* bc  = (const float*)d_in[13];
    const float* bo  = (const float*)d_in[14];

    float* ws     = (float*)d_ws;
    float* hbuf   = ws + OFF_H;
    float* cstate = ws + OFF_C;
    int*   bar    = (int*)(ws + OFF_BAR);
    float* xpc    = ws + OFF_XPC;
    float* states = ws + OFF_STATES;
    float* outp   = (float*)d_out;

    k_init<<<256, 256, 0, stream>>>(hbuf, cstate, bar);
    for (int c = 0; c < 16; c++) {
        k_gemm0<<<256, 256, 0, stream>>>(x, Wi, Wf, Wg, Wc, bi, bfv, bg, bc,
                                         xpc, c * 32);
        k_scan32<<<257, 256, 0, stream>>>(Ui, Uf, Ug, Uc, xpc,
                                          hbuf, cstate, states, bar, c * 32);
    }
    k_gemm1<<<1024, 256, 0, stream>>>(states, Wo, bo, outp);
}

// Round 5
// 13172.581 us; speedup vs baseline: 1.3275x; 1.0356x over previous
//
#include <hip/hip_runtime.h>

// ---- workspace layout (float-element offsets), total ~84.4 MB ----
// hbuf   : f32 [2][32][1024]   ping-pong hidden state (256 KB)
// cstate : f32 [32][1024]      cell state             (128 KB)
// bar    : int[32768]          sync region (128 KB reserved):
//            prog[b]  : bar[b*16], b=0..511      (64 B apart, monotone)
//            gminrep  : bar[8192 + l*64], l=0..15 (replicated global min)
// xpc    : f32 [1024][4096]    x@W chunk (32 steps)   (16 MB)
// states : f32 [16384][1024]   all h_t, row = t*32+b  (64 MB)
#define OFF_H      0ull
#define OFF_C      65536ull
#define OFF_BAR    98304ull
#define OFF_XPC    131072ull
#define OFF_STATES 4325376ull

#define BAR_REL    8192

#define AL(p) __hip_atomic_load((p), __ATOMIC_RELAXED, __HIP_MEMORY_SCOPE_AGENT)
#define AS(p, v) __hip_atomic_store((p), (v), __ATOMIC_RELAXED, __HIP_MEMORY_SCOPE_AGENT)

// coherent 16B load bypassing L1/L2 (reads LLC-fresh data)
#define GLOAD4(dst, ptr) \
    asm volatile("global_load_dwordx4 %0, %1, off sc0 sc1" \
                 : "=v"(dst) : "v"(ptr) : "memory")

// drain ALL vmem (loads+stores); sched_barrier stops hoisting past it (rule #18)
#define WAIT_VM0() do { asm volatile("s_waitcnt vmcnt(0)" ::: "memory"); \
    __builtin_amdgcn_sched_barrier(0); } while (0)

// raw barrier: drain LDS ops only; global ops stay in flight
#define BARRIER_LDS() do { asm volatile("s_waitcnt lgkmcnt(0)" ::: "memory"); \
    __builtin_amdgcn_s_barrier(); \
    __builtin_amdgcn_sched_barrier(0); } while (0)

static __device__ inline float sigmoidf_(float x) { return 1.f / (1.f + __expf(-x)); }
static __device__ inline float tanhf_(float x) { return 1.f - 2.f / (1.f + __expf(2.f * x)); }

// ---------------------------------------------------------------------------
// init: zero hbuf (65536 f32), cstate (32768 f32), bar (16384 ints used).
// ---------------------------------------------------------------------------
__global__ __launch_bounds__(256) void k_init(float* hb, float* cs, int* bar) {
    int i = blockIdx.x * 256 + threadIdx.x;
    hb[i] = 0.f;
    if (i < 32768) cs[i] = 0.f;
    if (i < 16384) bar[i] = 0;
}

// ---------------------------------------------------------------------------
// gemm0 (one 32-step chunk): xpc[Rl][4096] = x[b][t0+(Rl>>5)][:] @ [Wi|Wf|Wg|Wc] + b
// (unchanged, green)
// ---------------------------------------------------------------------------
__global__ __launch_bounds__(256) void k_gemm0(
    const float* __restrict__ x,
    const float* __restrict__ Wi, const float* __restrict__ Wf,
    const float* __restrict__ Wg, const float* __restrict__ Wc,
    const float* __restrict__ bi, const float* __restrict__ bfv,
    const float* __restrict__ bg, const float* __restrict__ bc,
    float* __restrict__ xpc, int t0)
{
    __shared__ float Ash[16 * 128];
    __shared__ float Bsh[16 * 128];
    int tid = threadIdx.x;
    int bm = blockIdx.x >> 5, bn = blockIdx.x & 31;
    int r0 = bm * 128, n0 = bn * 128;
    int gate = bn >> 3;
    int nloc = (bn & 7) * 128;
    const float* W; const float* bias;
    if (gate == 0)      { W = Wi; bias = bi; }
    else if (gate == 1) { W = Wf; bias = bfv; }
    else if (gate == 2) { W = Wg; bias = bg; }
    else                { W = Wc; bias = bc; }

    int mg = tid >> 4, ng = tid & 15;
    int m0 = mg * 8, n0l = ng * 8;
    int sm = tid >> 1, skh = (tid & 1) * 8;
    int sk = tid >> 4, snof = (tid & 15) * 8;
    int Ra = r0 + sm;
    const float* aptr = x + (size_t)(Ra & 31) * 524288
                          + (size_t)(t0 + (Ra >> 5)) * 1024 + skh;

    float acc[8][8];
    for (int i = 0; i < 8; i++)
        for (int j = 0; j < 8; j++) acc[i][j] = 0.f;

    for (int k0 = 0; k0 < 1024; k0 += 16) {
        float4 av0 = *(const float4*)(aptr + k0);
        float4 av1 = *(const float4*)(aptr + k0 + 4);
        float4 bv0 = *(const float4*)(W + (size_t)(k0 + sk) * 1024 + nloc + snof);
        float4 bv1 = *(const float4*)(W + (size_t)(k0 + sk) * 1024 + nloc + snof + 4);
        Ash[(skh + 0) * 128 + sm] = av0.x;
        Ash[(skh + 1) * 128 + sm] = av0.y;
        Ash[(skh + 2) * 128 + sm] = av0.z;
        Ash[(skh + 3) * 128 + sm] = av0.w;
        Ash[(skh + 4) * 128 + sm] = av1.x;
        Ash[(skh + 5) * 128 + sm] = av1.y;
        Ash[(skh + 6) * 128 + sm] = av1.z;
        Ash[(skh + 7) * 128 + sm] = av1.w;
        *(float4*)&Bsh[sk * 128 + snof] = bv0;
        *(float4*)&Bsh[sk * 128 + snof + 4] = bv1;
        __syncthreads();
#pragma unroll
        for (int k = 0; k < 16; k++) {
            float4 a0 = *(const float4*)&Ash[k * 128 + m0];
            float4 a1 = *(const float4*)&Ash[k * 128 + m0 + 4];
            float4 b0 = *(const float4*)&Bsh[k * 128 + n0l];
            float4 b1 = *(const float4*)&Bsh[k * 128 + n0l + 4];
            float aa[8], bb[8];
            aa[0] = a0.x; aa[1] = a0.y; aa[2] = a0.z; aa[3] = a0.w;
            aa[4] = a1.x; aa[5] = a1.y; aa[6] = a1.z; aa[7] = a1.w;
            bb[0] = b0.x; bb[1] = b0.y; bb[2] = b0.z; bb[3] = b0.w;
            bb[4] = b1.x; bb[5] = b1.y; bb[6] = b1.z; bb[7] = b1.w;
#pragma unroll
            for (int i = 0; i < 8; i++)
#pragma unroll
                for (int j = 0; j < 8; j++)
                    acc[i][j] = __builtin_fmaf(aa[i], bb[j], acc[i][j]);
        }
        __syncthreads();
    }
    float fbs[8];
#pragma unroll
    for (int j = 0; j < 8; j++) fbs[j] = bias[nloc + n0l + j];
    for (int i = 0; i < 8; i++) {
        size_t rowoff = (size_t)(r0 + m0 + i) * 4096 + n0 + n0l;
#pragma unroll
        for (int j = 0; j < 8; j++)
            xpc[rowoff + j] = acc[i][j] + fbs[j];
    }
}

// ---------------------------------------------------------------------------
// k_scan32 (2-BLOCKS/CU REWORK):
// 512 worker blocks x 128 thr (2 waves) + 1 sequencer. Block = 2 cols,
// wave = 2 gates x 2 cols. 2 blocks/CU -> independent pass-pipelines
// overlap each other's latency (R4 was 1 block/CU: all serial segments
// exposed). Same pass-level flow control as R4 (monotone prog, gmin gate,
// NEED = A-7, 9-pass overwrite margin).
//  - staging: asm global_load_dwordx4 sc0 sc1 (LLC-coherent 16B) -> regs,
//    committed to LDS behind a vmcnt(0)+sched_barrier guard.
//  - prog publish rides the NEXT pass's COMMIT vmcnt(0): owner tail has no
//    store-ack wait before a barrier.
//  - butterfly: merged 16-value shfl reduction (bits0-3) + 2 folds.
// ---------------------------------------------------------------------------
__global__ __launch_bounds__(128, 2) void k_scan32(
    const float* __restrict__ Ui, const float* __restrict__ Uf,
    const float* __restrict__ Ug, const float* __restrict__ Uc,
    const float* __restrict__ xpc,
    float* hbuf, float* cstate, float* states, int* bar, int t0)
{
    int tid = threadIdx.x;

    // ---- sequencer block: min over 512 prog -> 16 replicated gmin lines ----
    if (blockIdx.x == 512) {
        if (tid < 64) {
            int endv = (t0 + 32) * 8;
            for (;;) {
                int m = 0x7fffffff;
#pragma unroll
                for (int i = 0; i < 8; i++)
                    m = min(m, AL(&bar[(tid + i * 64) * 16]));
                m = min(m, __shfl_xor(m, 1, 64));
                m = min(m, __shfl_xor(m, 2, 64));
                m = min(m, __shfl_xor(m, 4, 64));
                m = min(m, __shfl_xor(m, 8, 64));
                m = min(m, __shfl_xor(m, 16, 64));
                m = min(m, __shfl_xor(m, 32, 64));
                if (tid < 16) AS(&bar[BAR_REL + tid * 64], m);
                if (m >= endv) break;
            }
        }
        return;
    }

    __shared__ float hsh[2][4][1024];  // 32 KB double-buffered pass tile
    __shared__ float zfin[2][32];      // parity ping-pong [b*8 + c*4 + g]
    __shared__ float csh[64];          // c-state [p*8 + owner(8)]

    int wv = tid >> 6;                 // wave -> gate pair {2wv, 2wv+1}
    int ku = tid & 63;                 // lane = k-group (k = j*256+ku*4+i)
    int col0 = ((((blockIdx.x & 7) << 6) | (blockIdx.x >> 3)) << 1);  // XCD swizzle
    const float* Bu0 = (wv == 0) ? Ui : Ug;
    const float* Bu1 = (wv == 0) ? Uf : Uc;

    // persistent U slice: ur[gl][c][j].i = U_{2wv+gl}[j*256+ku*4+i][col0+c]
    float4 ur[2][2][4];
#pragma unroll
    for (int gl = 0; gl < 2; gl++) {
        const float* Bu = gl ? Bu1 : Bu0;
#pragma unroll
        for (int c = 0; c < 2; c++)
#pragma unroll
            for (int j = 0; j < 4; j++) {
                size_t kb = (size_t)(j * 256 + ku * 4);
                float4 u;
                u.x = Bu[(kb + 0) * 1024 + col0 + c];
                u.y = Bu[(kb + 1) * 1024 + col0 + c];
                u.z = Bu[(kb + 2) * 1024 + col0 + c];
                u.w = Bu[(kb + 3) * 1024 + col0 + c];
                ur[gl][c][j] = u;
            }
    }

    // owners: tid<8, o=tid: b=o>>1, c=o&1
    if (tid < 8) {
        for (int p = 0; p < 8; p++)
            csh[p * 8 + tid] = cstate[(size_t)(p * 4 + (tid >> 1)) * 1024 + col0 + (tid & 1)];
    }

    int* gml = &bar[BAR_REL + (blockIdx.x & 15) * 64];
    int gv = AL(gml);
    float4 gA[8], gB[8];

#define STAGE(g, Qv)                                                          \
    if ((Qv) < 256) {                                                         \
        int need_ = t0 * 8 + (Qv) - 7;                                        \
        if (gv < need_) {                                                     \
            do { gv = AL(gml); if (gv >= need_) break;                        \
                 __builtin_amdgcn_s_sleep(2); } while (1);                    \
        }                                                                     \
        const float* hb_ = hbuf + (size_t)((((Qv) >> 3)) & 1) * 32768         \
                         + (size_t)(((Qv) & 7) * 4) * 1024;                   \
        _Pragma("unroll")                                                     \
        for (int q = 0; q < 8; q++) {                                         \
            int idx = tid + q * 128;                                          \
            const float* p_ = hb_ + (size_t)(idx >> 8) * 1024 + (idx & 255) * 4; \
            GLOAD4(g[q], p_);                                                 \
        }                                                                     \
    }

// COMMIT(g,Qv): guard staged regs (vmcnt0 also drains pass Qv-1's h stores,
// so prog publish for pass Qv-1 rides here), write LDS tile, barrier.
#define COMMIT(g, Qv)                                                         \
    {                                                                         \
        WAIT_VM0();                                                           \
        if (tid == 0) AS(&bar[blockIdx.x * 16], t0 * 8 + (Qv));               \
        _Pragma("unroll")                                                     \
        for (int q = 0; q < 8; q++) {                                         \
            int idx = tid + q * 128;                                          \
            *(float4*)&hsh[(Qv) & 1][idx >> 8][(idx & 255) * 4] = g[q];       \
        }                                                                     \
        BARRIER_LDS();                                                        \
    }

#define PASS(Qv)                                                              \
    {                                                                         \
        int tt_ = (Qv) >> 3, p_ = (Qv) & 7;                                   \
        float xg0 = 0.f, xg1 = 0.f, xg2 = 0.f, xg3 = 0.f;                     \
        if (tid < 8) {                                                        \
            const float* xr = xpc + (size_t)(tt_ * 32 + p_ * 4 + (tid >> 1)) * 4096 \
                            + col0 + (tid & 1);                               \
            xg0 = xr[0]; xg1 = xr[1024]; xg2 = xr[2048]; xg3 = xr[3072];      \
        }                                                                     \
        float w_[16];                                                         \
        _Pragma("unroll")                                                     \
        for (int v = 0; v < 16; v++) w_[v] = 0.f;                             \
        _Pragma("unroll")                                                     \
        for (int b = 0; b < 4; b++) {                                         \
            _Pragma("unroll")                                                 \
            for (int j = 0; j < 4; j++) {                                     \
                float4 hv = *(const float4*)&hsh[(Qv) & 1][b][j * 256 + ku * 4]; \
                _Pragma("unroll")                                             \
                for (int gl = 0; gl < 2; gl++)                                \
                _Pragma("unroll")                                             \
                for (int c = 0; c < 2; c++) {                                 \
                    float4 u = ur[gl][c][j];                                  \
                    int v = b * 4 + gl * 2 + c;                               \
                    w_[v] = __builtin_fmaf(hv.x, u.x, w_[v]);                 \
                    w_[v] = __builtin_fmaf(hv.y, u.y, w_[v]);                 \
                    w_[v] = __builtin_fmaf(hv.z, u.z, w_[v]);                 \
                    w_[v] = __builtin_fmaf(hv.w, u.w, w_[v]);                 \
                }                                                             \
            }                                                                 \
        }                                                                     \
        /* merged butterfly: value-bit k <- lane-bit k; lane l ends S[l&15] */ \
        float u_[8];                                                          \
        _Pragma("unroll")                                                     \
        for (int i = 0; i < 8; i++) {                                         \
            float a = w_[2 * i], b = w_[2 * i + 1];                           \
            float x = (ku & 1) ? a : b;                                       \
            float y = __shfl_xor(x, 1, 64);                                   \
            u_[i] = ((ku & 1) ? b : a) + y;                                   \
        }                                                                     \
        float v_[4];                                                          \
        _Pragma("unroll")                                                     \
        for (int i = 0; i < 4; i++) {                                         \
            float a = u_[2 * i], b = u_[2 * i + 1];                           \
            float x = (ku & 2) ? a : b;                                       \
            float y = __shfl_xor(x, 2, 64);                                   \
            v_[i] = ((ku & 2) ? b : a) + y;                                   \
        }                                                                     \
        float s_[2];                                                          \
        _Pragma("unroll")                                                     \
        for (int i = 0; i < 2; i++) {                                         \
            float a = v_[2 * i], b = v_[2 * i + 1];                           \
            float x = (ku & 4) ? a : b;                                       \
            float y = __shfl_xor(x, 4, 64);                                   \
            s_[i] = ((ku & 4) ? b : a) + y;                                   \
        }                                                                     \
        float r_;                                                             \
        {                                                                     \
            float a = s_[0], b = s_[1];                                       \
            float x = (ku & 8) ? a : b;                                       \
            float y = __shfl_xor(x, 8, 64);                                   \
            r_ = ((ku & 8) ? b : a) + y;                                      \
        }                                                                     \
        r_ += __shfl_xor(r_, 16, 64);                                         \
        r_ += __shfl_xor(r_, 32, 64);                                         \
        if (ku < 16)                                                          \
            zfin[(Qv) & 1][(ku >> 2) * 8 + (ku & 1) * 4 + wv * 2 + ((ku >> 1) & 1)] = r_; \
        BARRIER_LDS();                                                        \
        if (tid < 8) {                                                        \
            int b8 = (tid >> 1) * 8, c4 = (tid & 1) * 4;                      \
            float zi = zfin[(Qv) & 1][b8 + c4 + 0] + xg0;                     \
            float zf = zfin[(Qv) & 1][b8 + c4 + 1] + xg1;                     \
            float zg = zfin[(Qv) & 1][b8 + c4 + 2] + xg2;                     \
            float zc = zfin[(Qv) & 1][b8 + c4 + 3] + xg3;                     \
            float ig = sigmoidf_(zi);                                         \
            float fg = sigmoidf_(zf);                                         \
            float gg = sigmoidf_(zg);   /* reference: sigmoid on g */         \
            float ct = tanhf_(zc);                                            \
            float cv = fg * csh[p_ * 8 + tid] + ig * ct;                      \
            csh[p_ * 8 + tid] = cv;                                           \
            float hv2 = gg * tanhf_(cv);                                      \
            int t_ = t0 + tt_;                                                \
            int bg_ = p_ * 4 + (tid >> 1);                                    \
            AS(&hbuf[(size_t)((t_ + 1) & 1) * 32768 + (size_t)bg_ * 1024      \
                     + col0 + (tid & 1)], hv2);                               \
            states[((size_t)t_ * 32 + bg_) * 1024 + col0 + (tid & 1)] = hv2;  \
        }                                                                     \
    }

    // prologue: stage passes 0,1 (gated on prior-chunk gmin, valid: Q<8)
    STAGE(gA, 0)
    STAGE(gB, 1)

#pragma unroll 1
    for (int Q = 0; Q < 256; Q += 2) {
        COMMIT(gA, Q)
        STAGE(gA, Q + 2)
        PASS(Q)
        COMMIT(gB, Q + 1)
        STAGE(gB, Q + 3)
        PASS(Q + 1)
    }

    // final drain + publish chunk completion
    WAIT_VM0();
    if (tid == 0) AS(&bar[blockIdx.x * 16], t0 * 8 + 256);

    // persist c-state (plain; kernel-end flush)
    if (tid < 8) {
        for (int p = 0; p < 8; p++)
            cstate[(size_t)(p * 4 + (tid >> 1)) * 1024 + col0 + (tid & 1)] = csh[p * 8 + tid];
    }
#undef STAGE
#undef COMMIT
#undef PASS
}

// ---------------------------------------------------------------------------
// gemm1: out[b][t][:] = relu(states[t*32+b][:] @ Wo + bo)  (unchanged, green)
// ---------------------------------------------------------------------------
__global__ __launch_bounds__(256) void k_gemm1(
    const float* __restrict__ A, const float* __restrict__ Wo,
    const float* __restrict__ bo, float* __restrict__ outp)
{
    __shared__ float Ash[16 * 128];
    __shared__ float Bsh[16 * 128];
    int tid = threadIdx.x;
    int bm = blockIdx.x >> 3, bn = blockIdx.x & 7;
    int r0 = bm * 128, n0 = bn * 128;
    int mg = tid >> 4, ng = tid & 15;
    int m0 = mg * 8, n0l = ng * 8;
    int sm = tid >> 1, skh = (tid & 1) * 8;
    int sk = tid >> 4, snof = (tid & 15) * 8;
    const float* aptr = A + (size_t)(r0 + sm) * 1024 + skh;

    float acc[8][8];
    for (int i = 0; i < 8; i++)
        for (int j = 0; j < 8; j++) acc[i][j] = 0.f;

    for (int k0 = 0; k0 < 1024; k0 += 16) {
        float4 av0 = *(const float4*)(aptr + k0);
        float4 av1 = *(const float4*)(aptr + k0 + 4);
        float4 bv0 = *(const float4*)(Wo + (size_t)(k0 + sk) * 1024 + n0 + snof);
        float4 bv1 = *(const float4*)(Wo + (size_t)(k0 + sk) * 1024 + n0 + snof + 4);
        Ash[(skh + 0) * 128 + sm] = av0.x;
        Ash[(skh + 1) * 128 + sm] = av0.y;
        Ash[(skh + 2) * 128 + sm] = av0.z;
        Ash[(skh + 3) * 128 + sm] = av0.w;
        Ash[(skh + 4) * 128 + sm] = av1.x;
        Ash[(skh + 5) * 128 + sm] = av1.y;
        Ash[(skh + 6) * 128 + sm] = av1.z;
        Ash[(skh + 7) * 128 + sm] = av1.w;
        *(float4*)&Bsh[sk * 128 + snof] = bv0;
        *(float4*)&Bsh[sk * 128 + snof + 4] = bv1;
        __syncthreads();
#pragma unroll
        for (int k = 0; k < 16; k++) {
            float4 a0 = *(const float4*)&Ash[k * 128 + m0];
            float4 a1 = *(const float4*)&Ash[k * 128 + m0 + 4];
            float4 b0 = *(const float4*)&Bsh[k * 128 + n0l];
            float4 b1 = *(const float4*)&Bsh[k * 128 + n0l + 4];
            float aa[8], bb[8];
            aa[0] = a0.x; aa[1] = a0.y; aa[2] = a0.z; aa[3] = a0.w;
            aa[4] = a1.x; aa[5] = a1.y; aa[6] = a1.z; aa[7] = a1.w;
            bb[0] = b0.x; bb[1] = b0.y; bb[2] = b0.z; bb[3] = b0.w;
            bb[4] = b1.x; bb[5] = b1.y; bb[6] = b1.z; bb[7] = b1.w;
#pragma unroll
            for (int i = 0; i < 8; i++)
#pragma unroll
                for (int j = 0; j < 8; j++)
                    acc[i][j] = __builtin_fmaf(aa[i], bb[j], acc[i][j]);
        }
        __syncthreads();
    }
    float fbs[8];
#pragma unroll
    for (int j = 0; j < 8; j++) fbs[j] = bo[n0 + n0l + j];
    for (int i = 0; i < 8; i++) {
        int R = r0 + m0 + i;
        size_t rowoff = (size_t)(R & 31) * 524288 + (size_t)(R >> 5) * 1024 + n0 + n0l;
#pragma unroll
        for (int j = 0; j < 8; j++) {
            float v = acc[i][j] + fbs[j];
            outp[rowoff + j] = v > 0.f ? v : 0.f;
        }
    }
}

extern "C" void kernel_launch(void* const* d_in, const int* in_sizes, int n_in,
                              void* d_out, int out_size, void* d_ws, size_t ws_size,
                              hipStream_t stream)
{
    const float* x   = (const float*)d_in[0];
    const float* Wi  = (const float*)d_in[1];
    const float* Ui  = (const float*)d_in[2];
    const float* Wf  = (const float*)d_in[3];
    const float* Uf  = (const float*)d_in[4];
    const float* Wg  = (const float*)d_in[5];
    const float* Ug  = (const float*)d_in[6];
    const float* Wc  = (const float*)d_in[7];
    const float* Uc  = (const float*)d_in[8];
    const float* Wo  = (const float*)d_in[9];
    const float* bi  = (const float*)d_in[10];
    const float* bfv = (const float*)d_in[11];
    const float* bg  = (const float*)d_in[12];
    const float* bc  = (const float*)d_in[13];
    const float* bo  = (const float*)d_in[14];

    float* ws     = (float*)d_ws;
    float* hbuf   = ws + OFF_H;
    float* cstate = ws + OFF_C;
    int*   bar    = (int*)(ws + OFF_BAR);
    float* xpc    = ws + OFF_XPC;
    float* states = ws + OFF_STATES;
    float* outp   = (float*)d_out;

    k_init<<<256, 256, 0, stream>>>(hbuf, cstate, bar);
    for (int c = 0; c < 16; c++) {
        k_gemm0<<<256, 256, 0, stream>>>(x, Wi, Wf, Wg, Wc, bi, bfv, bg, bc,
                                         xpc, c * 32);
        k_scan32<<<513, 128, 0, stream>>>(Ui, Uf, Ug, Uc, xpc,
                                          hbuf, cstate, states, bar, c * 32);
    }
    k_gemm1<<<1024, 256, 0, stream>>>(states, Wo, bo, outp);
}

// Round 6
// 10599.402 us; speedup vs baseline: 1.6498x; 1.2428x over previous
//
#include <hip/hip_runtime.h>

// ---- workspace layout (float-element offsets), total ~84.4 MB ----
// hbuf   : f32 [2][32][1024]   ping-pong hidden state (256 KB)
// cstate : f32 [32][1024]      cell state             (128 KB)
// bar    : int[32768]          sync region (128 KB reserved):
//            prog[b]  : bar[b*16], b=0..511      (64 B apart, monotone)
//            gminrep  : bar[8192 + l*64], l=0..15 (replicated global min)
//            dump     : bar[16384..32767]        (full-exec store dump area)
// xpc    : f32 [1024][4096]    x@W chunk (32 steps)   (16 MB)
// states : f32 [16384][1024]   all h_t, row = t*32+b  (64 MB)
#define OFF_H      0ull
#define OFF_C      65536ull
#define OFF_BAR    98304ull
#define OFF_XPC    131072ull
#define OFF_STATES 4325376ull

#define BAR_REL    8192
#define BAR_DUMP   16384

#define AL(p) __hip_atomic_load((p), __ATOMIC_RELAXED, __HIP_MEMORY_SCOPE_AGENT)
#define AS(p, v) __hip_atomic_store((p), (v), __ATOMIC_RELAXED, __HIP_MEMORY_SCOPE_AGENT)

// coherent LLC-direct loads (invisible to compiler's waitcnt tracking)
#define GLOAD4(dst, ptr) \
    asm volatile("global_load_dwordx4 %0, %1, off sc0 sc1" \
                 : "=v"(dst) : "v"(ptr) : "memory")
#define GLOADF(dst, ptr) \
    asm volatile("global_load_dword %0, %1, off sc0 sc1" \
                 : "=v"(dst) : "v"(ptr) : "memory")
#define GLOADI(dst, ptr) \
    asm volatile("global_load_dword %0, %1, off sc0 sc1" \
                 : "=v"(dst) : "v"(ptr) : "memory")

// counted vmem wait + scheduling fence (rule #18)
#define WAIT_VMN_(n) asm volatile("s_waitcnt vmcnt(" #n ")" ::: "memory")
#define WAIT_VMN(n) do { WAIT_VMN_(n); __builtin_amdgcn_sched_barrier(0); } while (0)

// raw barrier: drain LDS ops only; global ops stay in flight
#define BARRIER_LDS() do { asm volatile("s_waitcnt lgkmcnt(0)" ::: "memory"); \
    __builtin_amdgcn_s_barrier(); \
    __builtin_amdgcn_sched_barrier(0); } while (0)

static __device__ inline float sigmoidf_(float x) { return 1.f / (1.f + __expf(-x)); }
static __device__ inline float tanhf_(float x) { return 1.f - 2.f / (1.f + __expf(2.f * x)); }

// ---------------------------------------------------------------------------
// init: zero hbuf (65536 f32), cstate (32768 f32), bar (16384 ints used).
// ---------------------------------------------------------------------------
__global__ __launch_bounds__(256) void k_init(float* hb, float* cs, int* bar) {
    int i = blockIdx.x * 256 + threadIdx.x;
    hb[i] = 0.f;
    if (i < 32768) cs[i] = 0.f;
    if (i < 16384) bar[i] = 0;
}

// ---------------------------------------------------------------------------
// gemm0 (one 32-step chunk): xpc[Rl][4096] = x[b][t0+(Rl>>5)][:] @ [Wi|Wf|Wg|Wc] + b
// (unchanged, green)
// ---------------------------------------------------------------------------
__global__ __launch_bounds__(256) void k_gemm0(
    const float* __restrict__ x,
    const float* __restrict__ Wi, const float* __restrict__ Wf,
    const float* __restrict__ Wg, const float* __restrict__ Wc,
    const float* __restrict__ bi, const float* __restrict__ bfv,
    const float* __restrict__ bg, const float* __restrict__ bc,
    float* __restrict__ xpc, int t0)
{
    __shared__ float Ash[16 * 128];
    __shared__ float Bsh[16 * 128];
    int tid = threadIdx.x;
    int bm = blockIdx.x >> 5, bn = blockIdx.x & 31;
    int r0 = bm * 128, n0 = bn * 128;
    int gate = bn >> 3;
    int nloc = (bn & 7) * 128;
    const float* W; const float* bias;
    if (gate == 0)      { W = Wi; bias = bi; }
    else if (gate == 1) { W = Wf; bias = bfv; }
    else if (gate == 2) { W = Wg; bias = bg; }
    else                { W = Wc; bias = bc; }

    int mg = tid >> 4, ng = tid & 15;
    int m0 = mg * 8, n0l = ng * 8;
    int sm = tid >> 1, skh = (tid & 1) * 8;
    int sk = tid >> 4, snof = (tid & 15) * 8;
    int Ra = r0 + sm;
    const float* aptr = x + (size_t)(Ra & 31) * 524288
                          + (size_t)(t0 + (Ra >> 5)) * 1024 + skh;

    float acc[8][8];
    for (int i = 0; i < 8; i++)
        for (int j = 0; j < 8; j++) acc[i][j] = 0.f;

    for (int k0 = 0; k0 < 1024; k0 += 16) {
        float4 av0 = *(const float4*)(aptr + k0);
        float4 av1 = *(const float4*)(aptr + k0 + 4);
        float4 bv0 = *(const float4*)(W + (size_t)(k0 + sk) * 1024 + nloc + snof);
        float4 bv1 = *(const float4*)(W + (size_t)(k0 + sk) * 1024 + nloc + snof + 4);
        Ash[(skh + 0) * 128 + sm] = av0.x;
        Ash[(skh + 1) * 128 + sm] = av0.y;
        Ash[(skh + 2) * 128 + sm] = av0.z;
        Ash[(skh + 3) * 128 + sm] = av0.w;
        Ash[(skh + 4) * 128 + sm] = av1.x;
        Ash[(skh + 5) * 128 + sm] = av1.y;
        Ash[(skh + 6) * 128 + sm] = av1.z;
        Ash[(skh + 7) * 128 + sm] = av1.w;
        *(float4*)&Bsh[sk * 128 + snof] = bv0;
        *(float4*)&Bsh[sk * 128 + snof + 4] = bv1;
        __syncthreads();
#pragma unroll
        for (int k = 0; k < 16; k++) {
            float4 a0 = *(const float4*)&Ash[k * 128 + m0];
            float4 a1 = *(const float4*)&Ash[k * 128 + m0 + 4];
            float4 b0 = *(const float4*)&Bsh[k * 128 + n0l];
            float4 b1 = *(const float4*)&Bsh[k * 128 + n0l + 4];
            float aa[8], bb[8];
            aa[0] = a0.x; aa[1] = a0.y; aa[2] = a0.z; aa[3] = a0.w;
            aa[4] = a1.x; aa[5] = a1.y; aa[6] = a1.z; aa[7] = a1.w;
            bb[0] = b0.x; bb[1] = b0.y; bb[2] = b0.z; bb[3] = b0.w;
            bb[4] = b1.x; bb[5] = b1.y; bb[6] = b1.z; bb[7] = b1.w;
#pragma unroll
            for (int i = 0; i < 8; i++)
#pragma unroll
                for (int j = 0; j < 8; j++)
                    acc[i][j] = __builtin_fmaf(aa[i], bb[j], acc[i][j]);
        }
        __syncthreads();
    }
    float fbs[8];
#pragma unroll
    for (int j = 0; j < 8; j++) fbs[j] = bias[nloc + n0l + j];
    for (int i = 0; i < 8; i++) {
        size_t rowoff = (size_t)(r0 + m0 + i) * 4096 + n0 + n0l;
#pragma unroll
        for (int j = 0; j < 8; j++)
            xpc[rowoff + j] = acc[i][j] + fbs[j];
    }
}

// ---------------------------------------------------------------------------
// k_scan32 (COUNTED-VMCNT REWORK):
// Same topology as R5 (512 worker blocks x 128 thr + sequencer, pass-level
// flow control). Fix: R5's COMMIT vmcnt(0) drained the just-issued prefetch
// and the store ACKs every pass (+compiler vmcnt(0) on xpc loads) — the whole
// 2.75 us/pass. Now:
//  - ALL in-loop vmem is inline-asm (counts are ours); owner stores are
//    full-exec with address-select to a dump area => deterministic per-wave
//    instruction counts: wave0 stage=13 (8 h + 4 xpc + 1 gmin-refresh),
//    pass-stores=2; wave1 stage=9, stores=0.
//  - iteration: P(Q) | STAGE(Q+2) | COMMIT(Q+1). Steady-state queue at
//    COMMIT(n), wave0: [P(n-2)2][S(n)13][pub1][P(n-1)2][S(n+1)13] ->
//    vmcnt(15) retires exactly {P(n-2), S(n), pub}; prefetch S(n+1) and
//    fresh stores P(n-1) stay in flight. wave1: vmcnt(9). First commit: 13/9.
//  - publish lags one pass: COMMIT(n) publishes t0*8+n-1 (needs stores(n-2),
//    which vmcnt(15) provably retired). Epilogue full-drain publishes +256.
//  - gmin poll: asm refresh issued per stage, consumed 2 stages later
//    (retired by the intervening commit) => steady-state gate check is free.
// ---------------------------------------------------------------------------
__global__ __launch_bounds__(128, 2) void k_scan32(
    const float* __restrict__ Ui, const float* __restrict__ Uf,
    const float* __restrict__ Ug, const float* __restrict__ Uc,
    const float* __restrict__ xpc,
    float* hbuf, float* cstate, float* states, int* bar, int t0)
{
    int tid = threadIdx.x;

    // ---- sequencer block: min over 512 prog -> 16 replicated gmin lines ----
    if (blockIdx.x == 512) {
        if (tid < 64) {
            int endv = (t0 + 32) * 8;
            for (;;) {
                int m = 0x7fffffff;
#pragma unroll
                for (int i = 0; i < 8; i++)
                    m = min(m, AL(&bar[(tid + i * 64) * 16]));
                m = min(m, __shfl_xor(m, 1, 64));
                m = min(m, __shfl_xor(m, 2, 64));
                m = min(m, __shfl_xor(m, 4, 64));
                m = min(m, __shfl_xor(m, 8, 64));
                m = min(m, __shfl_xor(m, 16, 64));
                m = min(m, __shfl_xor(m, 32, 64));
                if (tid < 16) AS(&bar[BAR_REL + tid * 64], m);
                if (m >= endv) break;
            }
        }
        return;
    }

    __shared__ float hsh[2][4][1024];  // 32 KB double-buffered pass tile
    __shared__ float zfin[2][32];      // parity ping-pong [b*8 + c*4 + g]
    __shared__ float csh[64];          // c-state [p*8 + owner(8)]

    int wv = tid >> 6;                 // wave -> gate pair {2wv, 2wv+1}
    int ku = tid & 63;                 // lane = k-group (k = j*256+ku*4+i)
    int col0 = ((((blockIdx.x & 7) << 6) | (blockIdx.x >> 3)) << 1);  // XCD swizzle
    const float* Bu0 = (wv == 0) ? Ui : Ug;
    const float* Bu1 = (wv == 0) ? Uf : Uc;

    // persistent U slice: ur[gl][c][j].i = U_{2wv+gl}[j*256+ku*4+i][col0+c]
    float4 ur[2][2][4];
#pragma unroll
    for (int gl = 0; gl < 2; gl++) {
        const float* Bu = gl ? Bu1 : Bu0;
#pragma unroll
        for (int c = 0; c < 2; c++)
#pragma unroll
            for (int j = 0; j < 4; j++) {
                size_t kb = (size_t)(j * 256 + ku * 4);
                float4 u;
                u.x = Bu[(kb + 0) * 1024 + col0 + c];
                u.y = Bu[(kb + 1) * 1024 + col0 + c];
                u.z = Bu[(kb + 2) * 1024 + col0 + c];
                u.w = Bu[(kb + 3) * 1024 + col0 + c];
                ur[gl][c][j] = u;
            }
    }

    // owners: o=tid<8: b=o>>1, c=o&1
    if (tid < 8) {
        for (int p = 0; p < 8; p++)
            csh[p * 8 + tid] = cstate[(size_t)(p * 4 + (tid >> 1)) * 1024 + col0 + (tid & 1)];
    }

    int* gml = &bar[BAR_REL + (blockIdx.x & 15) * 64];
    // full-exec dump slots (lanes >= 8 store here)
    float* dumpA = (float*)&bar[BAR_DUMP + ((blockIdx.x & 63) << 6) + (tid & 63)];
    float* dumpB = (float*)&bar[BAR_DUMP + 4096 + ((blockIdx.x & 63) << 6) + (tid & 63)];

    // gmin pipeline: value checked at stage n was loaded at stage n-2
    // (provably retired by the commit directly preceding stage n).
    int rA = AL(gml);                  // compiler load, prologue only
    int rB = rA;
    float4 gA[8], gB[8];
    float xgA[4], xgB[4];

#define STAGE(g, xg, rv, Qv)                                                  \
    if ((Qv) < 256) {                                                         \
        int need_ = t0 * 8 + (Qv) - 7;                                        \
        if (rv < need_) {      /* rare: genuinely at the window edge */       \
            int s_;                                                           \
            for (;;) { s_ = AL(gml); if (s_ >= need_) break;                  \
                       __builtin_amdgcn_s_sleep(1); }                         \
            rv = s_;                                                          \
        }                                                                     \
        const float* hb_ = hbuf + (size_t)((((Qv) >> 3)) & 1) * 32768         \
                         + (size_t)(((Qv) & 7) * 4) * 1024;                   \
        _Pragma("unroll")                                                     \
        for (int q = 0; q < 8; q++) {                                         \
            int idx = tid + q * 128;                                          \
            const float* p_ = hb_ + (size_t)(idx >> 8) * 1024 + (idx & 255) * 4; \
            GLOAD4(g[q], p_);                                                 \
        }                                                                     \
        if (tid < 64) {        /* wave-uniform; full-exec, clamped owner */   \
            int o_ = tid & 7;                                                 \
            const float* xr = xpc + (size_t)((((Qv) >> 3) * 32) + ((Qv) & 7) * 4 \
                            + (o_ >> 1)) * 4096 + col0 + (o_ & 1);            \
            GLOADF(xg[0], xr);                                                \
            GLOADF(xg[1], xr + 1024);                                         \
            GLOADF(xg[2], xr + 2048);                                         \
            GLOADF(xg[3], xr + 3072);                                         \
        }                                                                     \
        GLOADI(rv, gml);       /* refresh, consumed 2 stages later */         \
    }

// COMMIT(g,Qv): counted wait (retires consumed stage + 2-pass-old stores,
// keeps prefetch + fresh stores in flight), publish lagged prog, LDS tile.
#define COMMIT(g, Qv, FIRST)                                                  \
    {                                                                         \
        if (tid < 64) { if (FIRST) { WAIT_VMN(13); } else { WAIT_VMN(15); } } \
        else          { WAIT_VMN(9); }                                        \
        if (!(FIRST) && (Qv) >= 2 && tid == 0)                                \
            AS(&bar[blockIdx.x * 16], t0 * 8 + (Qv) - 1);                     \
        _Pragma("unroll")                                                     \
        for (int q = 0; q < 8; q++) {                                         \
            int idx = tid + q * 128;                                          \
            *(float4*)&hsh[(Qv) & 1][idx >> 8][(idx & 255) * 4] = g[q];       \
        }                                                                     \
        BARRIER_LDS();                                                        \
    }

#define PASS(Qv, xg)                                                          \
    {                                                                         \
        int tt_ = (Qv) >> 3, p_ = (Qv) & 7;                                   \
        float w_[16];                                                         \
        _Pragma("unroll")                                                     \
        for (int v = 0; v < 16; v++) w_[v] = 0.f;                             \
        _Pragma("unroll")                                                     \
        for (int b = 0; b < 4; b++) {                                         \
            _Pragma("unroll")                                                 \
            for (int j = 0; j < 4; j++) {                                     \
                float4 hv = *(const float4*)&hsh[(Qv) & 1][b][j * 256 + ku * 4]; \
                _Pragma("unroll")                                             \
                for (int gl = 0; gl < 2; gl++)                                \
                _Pragma("unroll")                                             \
                for (int c = 0; c < 2; c++) {                                 \
                    float4 u = ur[gl][c][j];                                  \
                    int v = b * 4 + gl * 2 + c;                               \
                    w_[v] = __builtin_fmaf(hv.x, u.x, w_[v]);                 \
                    w_[v] = __builtin_fmaf(hv.y, u.y, w_[v]);                 \
                    w_[v] = __builtin_fmaf(hv.z, u.z, w_[v]);                 \
                    w_[v] = __builtin_fmaf(hv.w, u.w, w_[v]);                 \
                }                                                             \
            }                                                                 \
        }                                                                     \
        /* merged butterfly: value-bit k <- lane-bit k; lane l ends S[l&15] */ \
        float u_[8];                                                          \
        _Pragma("unroll")                                                     \
        for (int i = 0; i < 8; i++) {                                         \
            float a = w_[2 * i], b = w_[2 * i + 1];                           \
            float x = (ku & 1) ? a : b;                                       \
            float y = __shfl_xor(x, 1, 64);                                   \
            u_[i] = ((ku & 1) ? b : a) + y;                                   \
        }                                                                     \
        float v_[4];                                                          \
        _Pragma("unroll")                                                     \
        for (int i = 0; i < 4; i++) {                                         \
            float a = u_[2 * i], b = u_[2 * i + 1];                           \
            float x = (ku & 2) ? a : b;                                       \
            float y = __shfl_xor(x, 2, 64);                                   \
            v_[i] = ((ku & 2) ? b : a) + y;                                   \
        }                                                                     \
        float s_[2];                                                          \
        _Pragma("unroll")                                                     \
        for (int i = 0; i < 2; i++) {                                         \
            float a = v_[2 * i], b = v_[2 * i + 1];                           \
            float x = (ku & 4) ? a : b;                                       \
            float y = __shfl_xor(x, 4, 64);                                   \
            s_[i] = ((ku & 4) ? b : a) + y;                                   \
        }                                                                     \
        float r_;                                                             \
        {                                                                     \
            float a = s_[0], b = s_[1];                                       \
            float x = (ku & 8) ? a : b;                                       \
            float y = __shfl_xor(x, 8, 64);                                   \
            r_ = ((ku & 8) ? b : a) + y;                                      \
        }                                                                     \
        r_ += __shfl_xor(r_, 16, 64);                                         \
        r_ += __shfl_xor(r_, 32, 64);                                         \
        if (ku < 16)                                                          \
            zfin[(Qv) & 1][(ku >> 2) * 8 + (ku & 1) * 4 + wv * 2 + ((ku >> 1) & 1)] = r_; \
        BARRIER_LDS();                                                        \
        if (tid < 64) {        /* wave0: full-exec gate math, clamped */      \
            int o_ = tid & 7;                                                 \
            int b8 = (o_ >> 1) * 8, c4 = (o_ & 1) * 4;                        \
            float zi = zfin[(Qv) & 1][b8 + c4 + 0] + xg[0];                   \
            float zf = zfin[(Qv) & 1][b8 + c4 + 1] + xg[1];                   \
            float zg = zfin[(Qv) & 1][b8 + c4 + 2] + xg[2];                   \
            float zc = zfin[(Qv) & 1][b8 + c4 + 3] + xg[3];                   \
            float ig = sigmoidf_(zi);                                         \
            float fg = sigmoidf_(zf);                                         \
            float gg = sigmoidf_(zg);   /* reference: sigmoid on g */         \
            float ct = tanhf_(zc);                                            \
            float cv = fg * csh[p_ * 8 + o_] + ig * ct;                       \
            if (tid < 8) csh[p_ * 8 + tid] = cv;                              \
            float hv2 = gg * tanhf_(cv);                                      \
            int t_ = t0 + tt_;                                                \
            int bg_ = p_ * 4 + (o_ >> 1);                                     \
            float* ha_ = (tid < 8)                                            \
                ? &hbuf[(size_t)((t_ + 1) & 1) * 32768 + (size_t)bg_ * 1024 + col0 + (o_ & 1)] \
                : dumpA;                                                      \
            AS(ha_, hv2);                                                     \
            float* sa_ = (tid < 8)                                            \
                ? &states[((size_t)t_ * 32 + bg_) * 1024 + col0 + (o_ & 1)]   \
                : dumpB;                                                      \
            *sa_ = hv2;                                                       \
        }                                                                     \
    }

    // prologue: stage 0,1; commit 0
    STAGE(gA, xgA, rA, 0)
    STAGE(gB, xgB, rB, 1)
    COMMIT(gA, 0, 1)

#pragma unroll 1
    for (int Q = 0; Q < 256; Q += 2) {
        PASS(Q, xgA)
        STAGE(gA, xgA, rA, Q + 2)
        COMMIT(gB, Q + 1, 0)
        PASS(Q + 1, xgB)
        STAGE(gB, xgB, rB, Q + 3)
        if (Q + 2 < 256) { COMMIT(gA, Q + 2, 0) }
    }

    // epilogue: full drain, publish chunk completion
    WAIT_VMN(0);
    if (tid == 0) AS(&bar[blockIdx.x * 16], t0 * 8 + 256);

    // persist c-state (plain; kernel-end flush)
    if (tid < 8) {
        for (int p = 0; p < 8; p++)
            cstate[(size_t)(p * 4 + (tid >> 1)) * 1024 + col0 + (tid & 1)] = csh[p * 8 + tid];
    }
#undef STAGE
#undef COMMIT
#undef PASS
}

// ---------------------------------------------------------------------------
// gemm1: out[b][t][:] = relu(states[t*32+b][:] @ Wo + bo)  (unchanged, green)
// ---------------------------------------------------------------------------
__global__ __launch_bounds__(256) void k_gemm1(
    const float* __restrict__ A, const float* __restrict__ Wo,
    const float* __restrict__ bo, float* __restrict__ outp)
{
    __shared__ float Ash[16 * 128];
    __shared__ float Bsh[16 * 128];
    int tid = threadIdx.x;
    int bm = blockIdx.x >> 3, bn = blockIdx.x & 7;
    int r0 = bm * 128, n0 = bn * 128;
    int mg = tid >> 4, ng = tid & 15;
    int m0 = mg * 8, n0l = ng * 8;
    int sm = tid >> 1, skh = (tid & 1) * 8;
    int sk = tid >> 4, snof = (tid & 15) * 8;
    const float* aptr = A + (size_t)(r0 + sm) * 1024 + skh;

    float acc[8][8];
    for (int i = 0; i < 8; i++)
        for (int j = 0; j < 8; j++) acc[i][j] = 0.f;

    for (int k0 = 0; k0 < 1024; k0 += 16) {
        float4 av0 = *(const float4*)(aptr + k0);
        float4 av1 = *(const float4*)(aptr + k0 + 4);
        float4 bv0 = *(const float4*)(Wo + (size_t)(k0 + sk) * 1024 + n0 + snof);
        float4 bv1 = *(const float4*)(Wo + (size_t)(k0 + sk) * 1024 + n0 + snof + 4);
        Ash[(skh + 0) * 128 + sm] = av0.x;
        Ash[(skh + 1) * 128 + sm] = av0.y;
        Ash[(skh + 2) * 128 + sm] = av0.z;
        Ash[(skh + 3) * 128 + sm] = av0.w;
        Ash[(skh + 4) * 128 + sm] = av1.x;
        Ash[(skh + 5) * 128 + sm] = av1.y;
        Ash[(skh + 6) * 128 + sm] = av1.z;
        Ash[(skh + 7) * 128 + sm] = av1.w;
        *(float4*)&Bsh[sk * 128 + snof] = bv0;
        *(float4*)&Bsh[sk * 128 + snof + 4] = bv1;
        __syncthreads();
#pragma unroll
        for (int k = 0; k < 16; k++) {
            float4 a0 = *(const float4*)&Ash[k * 128 + m0];
            float4 a1 = *(const float4*)&Ash[k * 128 + m0 + 4];
            float4 b0 = *(const float4*)&Bsh[k * 128 + n0l];
            float4 b1 = *(const float4*)&Bsh[k * 128 + n0l + 4];
            float aa[8], bb[8];
            aa[0] = a0.x; aa[1] = a0.y; aa[2] = a0.z; aa[3] = a0.w;
            aa[4] = a1.x; aa[5] = a1.y; aa[6] = a1.z; aa[7] = a1.w;
            bb[0] = b0.x; bb[1] = b0.y; bb[2] = b0.z; bb[3] = b0.w;
            bb[4] = b1.x; bb[5] = b1.y; bb[6] = b1.z; bb[7] = b1.w;
#pragma unroll
            for (int i = 0; i < 8; i++)
#pragma unroll
                for (int j = 0; j < 8; j++)
                    acc[i][j] = __builtin_fmaf(aa[i], bb[j], acc[i][j]);
        }
        __syncthreads();
    }
    float fbs[8];
#pragma unroll
    for (int j = 0; j < 8; j++) fbs[j] = bo[n0 + n0l + j];
    for (int i = 0; i < 8; i++) {
        int R = r0 + m0 + i;
        size_t rowoff = (size_t)(R & 31) * 524288 + (size_t)(R >> 5) * 1024 + n0 + n0l;
#pragma unroll
        for (int j = 0; j < 8; j++) {
            float v = acc[i][j] + fbs[j];
            outp[rowoff + j] = v > 0.f ? v : 0.f;
        }
    }
}

extern "C" void kernel_launch(void* const* d_in, const int* in_sizes, int n_in,
                              void* d_out, int out_size, void* d_ws, size_t ws_size,
                              hipStream_t stream)
{
    const float* x   = (const float*)d_in[0];
    const float* Wi  = (const float*)d_in[1];
    const float* Ui  = (const float*)d_in[2];
    const float* Wf  = (const float*)d_in[3];
    const float* Uf  = (const float*)d_in[4];
    const float* Wg  = (const float*)d_in[5];
    const float* Ug  = (const float*)d_in[6];
    const float* Wc  = (const float*)d_in[7];
    const float* Uc  = (const float*)d_in[8];
    const float* Wo  = (const float*)d_in[9];
    const float* bi  = (const float*)d_in[10];
    const float* bfv = (const float*)d_in[11];
    const float* bg  = (const float*)d_in[12];
    const float* bc  = (const float*)d_in[13];
    const float* bo  = (const float*)d_in[14];

    float* ws     = (float*)d_ws;
    float* hbuf   = ws + OFF_H;
    float* cstate = ws + OFF_C;
    int*   bar    = (int*)(ws + OFF_BAR);
    float* xpc    = ws + OFF_XPC;
    float* states = ws + OFF_STATES;
    float* outp   = (float*)d_out;

    k_init<<<256, 256, 0, stream>>>(hbuf, cstate, bar);
    for (int c = 0; c < 16; c++) {
        k_gemm0<<<256, 256, 0, stream>>>(x, Wi, Wf, Wg, Wc, bi, bfv, bg, bc,
                                         xpc, c * 32);
        k_scan32<<<513, 128, 0, stream>>>(Ui, Uf, Ug, Uc, xpc,
                                          hbuf, cstate, states, bar, c * 32);
    }
    k_gemm1<<<1024, 256, 0, stream>>>(states, Wo, bo, outp);
}

// Round 9
// 8701.806 us; speedup vs baseline: 2.0096x; 1.2181x over previous
//
#include <hip/hip_runtime.h>

// ---- workspace layout (float-element offsets), total ~84.4 MB ----
// hbuf   : f32 [2][32][1024]   ping-pong hidden state (256 KB)
// cstate : f32 [32][1024]      cell state             (128 KB)
// bar    : int[32768]          sync region (128 KB reserved):
//            prog[b]  : bar[b*16], b=0..255      (64 B apart, monotone)
//            gminrep  : bar[8192 + l*64], l=0..15 (replicated global min)
// xpc    : f32 [1024][4096]    x@W chunk (32 steps)   (16 MB)
// states : f32 [16384][1024]   all h_t, row = t*32+b  (64 MB)
#define OFF_H      0ull
#define OFF_C      65536ull
#define OFF_BAR    98304ull
#define OFF_XPC    131072ull
#define OFF_STATES 4325376ull

#define BAR_REL    8192

#define AL(p) __hip_atomic_load((p), __ATOMIC_RELAXED, __HIP_MEMORY_SCOPE_AGENT)
#define AS(p, v) __hip_atomic_store((p), (v), __ATOMIC_RELAXED, __HIP_MEMORY_SCOPE_AGENT)

// coherent LLC-direct loads (invisible to compiler's waitcnt tracking)
#define GLOAD4(dst, ptr) \
    asm volatile("global_load_dwordx4 %0, %1, off sc0 sc1" \
                 : "=v"(dst) : "v"(ptr) : "memory")
#define GLOADF(dst, ptr) \
    asm volatile("global_load_dword %0, %1, off sc0 sc1" \
                 : "=v"(dst) : "v"(ptr) : "memory")
#define GLOADI(dst, ptr) \
    asm volatile("global_load_dword %0, %1, off sc0 sc1" \
                 : "=v"(dst) : "v"(ptr) : "memory")

// counted vmem wait + scheduling fence (rule #18)
#define WAIT_VMN_(n) asm volatile("s_waitcnt vmcnt(" #n ")" ::: "memory")
#define WAIT_VMN(n) do { WAIT_VMN_(n); __builtin_amdgcn_sched_barrier(0); } while (0)

// raw barrier: drain LDS ops only; global ops stay in flight
#define BARRIER_LDS() do { asm volatile("s_waitcnt lgkmcnt(0)" ::: "memory"); \
    __builtin_amdgcn_s_barrier(); \
    __builtin_amdgcn_sched_barrier(0); } while (0)

static __device__ inline float sigmoidf_(float x) { return 1.f / (1.f + __expf(-x)); }
static __device__ inline float tanhf_(float x) { return 1.f - 2.f / (1.f + __expf(2.f * x)); }

// ---------------------------------------------------------------------------
// init: zero hbuf (65536 f32), cstate (32768 f32), bar (16384 ints used).
// ---------------------------------------------------------------------------
__global__ __launch_bounds__(256) void k_init(float* hb, float* cs, int* bar) {
    int i = blockIdx.x * 256 + threadIdx.x;
    hb[i] = 0.f;
    if (i < 32768) cs[i] = 0.f;
    if (i < 16384) bar[i] = 0;
}

// ---------------------------------------------------------------------------
// gemm0 (one 32-step chunk): xpc[Rl][4096] = x[b][t0+(Rl>>5)][:] @ [Wi|Wf|Wg|Wc] + b
// (unchanged, green)
// ---------------------------------------------------------------------------
__global__ __launch_bounds__(256) void k_gemm0(
    const float* __restrict__ x,
    const float* __restrict__ Wi, const float* __restrict__ Wf,
    const float* __restrict__ Wg, const float* __restrict__ Wc,
    const float* __restrict__ bi, const float* __restrict__ bfv,
    const float* __restrict__ bg, const float* __restrict__ bc,
    float* __restrict__ xpc, int t0)
{
    __shared__ float Ash[16 * 128];
    __shared__ float Bsh[16 * 128];
    int tid = threadIdx.x;
    int bm = blockIdx.x >> 5, bn = blockIdx.x & 31;
    int r0 = bm * 128, n0 = bn * 128;
    int gate = bn >> 3;
    int nloc = (bn & 7) * 128;
    const float* W; const float* bias;
    if (gate == 0)      { W = Wi; bias = bi; }
    else if (gate == 1) { W = Wf; bias = bfv; }
    else if (gate == 2) { W = Wg; bias = bg; }
    else                { W = Wc; bias = bc; }

    int mg = tid >> 4, ng = tid & 15;
    int m0 = mg * 8, n0l = ng * 8;
    int sm = tid >> 1, skh = (tid & 1) * 8;
    int sk = tid >> 4, snof = (tid & 15) * 8;
    int Ra = r0 + sm;
    const float* aptr = x + (size_t)(Ra & 31) * 524288
                          + (size_t)(t0 + (Ra >> 5)) * 1024 + skh;

    float acc[8][8];
    for (int i = 0; i < 8; i++)
        for (int j = 0; j < 8; j++) acc[i][j] = 0.f;

    for (int k0 = 0; k0 < 1024; k0 += 16) {
        float4 av0 = *(const float4*)(aptr + k0);
        float4 av1 = *(const float4*)(aptr + k0 + 4);
        float4 bv0 = *(const float4*)(W + (size_t)(k0 + sk) * 1024 + nloc + snof);
        float4 bv1 = *(const float4*)(W + (size_t)(k0 + sk) * 1024 + nloc + snof + 4);
        Ash[(skh + 0) * 128 + sm] = av0.x;
        Ash[(skh + 1) * 128 + sm] = av0.y;
        Ash[(skh + 2) * 128 + sm] = av0.z;
        Ash[(skh + 3) * 128 + sm] = av0.w;
        Ash[(skh + 4) * 128 + sm] = av1.x;
        Ash[(skh + 5) * 128 + sm] = av1.y;
        Ash[(skh + 6) * 128 + sm] = av1.z;
        Ash[(skh + 7) * 128 + sm] = av1.w;
        *(float4*)&Bsh[sk * 128 + snof] = bv0;
        *(float4*)&Bsh[sk * 128 + snof + 4] = bv1;
        __syncthreads();
#pragma unroll
        for (int k = 0; k < 16; k++) {
            float4 a0 = *(const float4*)&Ash[k * 128 + m0];
            float4 a1 = *(const float4*)&Ash[k * 128 + m0 + 4];
            float4 b0 = *(const float4*)&Bsh[k * 128 + n0l];
            float4 b1 = *(const float4*)&Bsh[k * 128 + n0l + 4];
            float aa[8], bb[8];
            aa[0] = a0.x; aa[1] = a0.y; aa[2] = a0.z; aa[3] = a0.w;
            aa[4] = a1.x; aa[5] = a1.y; aa[6] = a1.z; aa[7] = a1.w;
            bb[0] = b0.x; bb[1] = b0.y; bb[2] = b0.z; bb[3] = b0.w;
            bb[4] = b1.x; bb[5] = b1.y; bb[6] = b1.z; bb[7] = b1.w;
#pragma unroll
            for (int i = 0; i < 8; i++)
#pragma unroll
                for (int j = 0; j < 8; j++)
                    acc[i][j] = __builtin_fmaf(aa[i], bb[j], acc[i][j]);
        }
        __syncthreads();
    }
    float fbs[8];
#pragma unroll
    for (int j = 0; j < 8; j++) fbs[j] = bias[nloc + n0l + j];
    for (int i = 0; i < 8; i++) {
        size_t rowoff = (size_t)(r0 + m0 + i) * 4096 + n0 + n0l;
#pragma unroll
        for (int j = 0; j < 8; j++)
            xpc[rowoff + j] = acc[i][j] + fbs[j];
    }
}

// ---------------------------------------------------------------------------
// k_scan32 (R6 structure SCALED: 4 cols/block, 8-batch passes):
// 256 worker blocks x 256 thr (4 waves) + 1 sequencer. Block = 4 cols.
// Wave wv: gate pair gp=wv&1 -> {2gp,2gp+1}, col pair cp=wv>>1 -> {2cp,2cp+1},
// covers ALL 8 batches of the pass: 512 FMA/lane (ur = 2g x 2c x 16k = 64 VGPR).
// Pass = 8 batches (4 passes/step, 128/chunk): per-pass fixed costs (2
// barriers, butterfly, commit waits) amortized over 2x work vs R6; h LLC
// broadcast halves (256 readers of each pass tile vs 512).
// Per-wave vmem counts per pass == R6 exactly:
//   wave0 stage = 13 (8 gA + 4 xg + 1 rv), stores 2 + pub 1; waves1-3 = 9, 0.
//   => R6's verified wait schedule transfers verbatim:
//   prologue (13,9)(15,9)(15,9)(16,9) -> steady (16,9) -> final (0,0).
// Dump-store hack DELETED: vmcnt counts instructions per wave; `if(tid<32)`
// branches are wave-deterministic (wave0 taken, waves1-3 skipped).
// Flow control (R6 scheme, re-derived for 4 passes/step):
//   pub at COMMIT(n) = t0*4 + n - 1 (wait provably retired pass n-2 stores);
//   NEED(Q) = t0*4 + Q - 3 (stage(Q) reads h written at pass Q-4);
//   overwrite distance 8 passes >= max spread ~5. Epilogue pub t0*4+128.
// ---------------------------------------------------------------------------
__global__ __launch_bounds__(256, 1) void k_scan32(
    const float* __restrict__ Ui, const float* __restrict__ Uf,
    const float* __restrict__ Ug, const float* __restrict__ Uc,
    const float* __restrict__ xpc,
    float* hbuf, float* cstate, float* states, int* bar, int t0)
{
    int tid = threadIdx.x;

    // ---- sequencer block: min over 256 prog -> 16 replicated gmin lines ----
    if (blockIdx.x == 256) {
        if (tid < 64) {
            int endv = t0 * 4 + 128;
            for (;;) {
                int m0 = AL(&bar[(tid * 4 + 0) * 16]);
                int m1 = AL(&bar[(tid * 4 + 1) * 16]);
                int m2 = AL(&bar[(tid * 4 + 2) * 16]);
                int m3 = AL(&bar[(tid * 4 + 3) * 16]);
                int m = min(min(m0, m1), min(m2, m3));
                m = min(m, __shfl_xor(m, 1, 64));
                m = min(m, __shfl_xor(m, 2, 64));
                m = min(m, __shfl_xor(m, 4, 64));
                m = min(m, __shfl_xor(m, 8, 64));
                m = min(m, __shfl_xor(m, 16, 64));
                m = min(m, __shfl_xor(m, 32, 64));
                if (tid < 16) AS(&bar[BAR_REL + tid * 64], m);
                if (m >= endv) break;
            }
        }
        return;
    }

    __shared__ float hsh[2][8][1024];  // 64 KB double-buffered 8-batch tile
    __shared__ float zfin[2][128];     // parity ping-pong [b*16 + g*4 + c]
    __shared__ float csh[4][32];       // c-state [pass-in-step][owner(32)]

    int wv = tid >> 6;                 // wave
    int ku = tid & 63;                 // lane: k-slice k = j*256+ku*4+i
    int gp = wv & 1, cp = wv >> 1;     // gate pair / col pair
    int col0 = ((((blockIdx.x & 7) << 5) | (blockIdx.x >> 3)) << 2);  // XCD swizzle

    // persistent U slice: ur[gl][cl][j].i = U_{2gp+gl}[j*256+ku*4+i][col0+2cp+cl]
    float4 ur[2][2][4];
    {
        const float* Bu0 = (gp == 0) ? Ui : Ug;
        const float* Bu1 = (gp == 0) ? Uf : Uc;
#pragma unroll
        for (int gl = 0; gl < 2; gl++) {
            const float* Bu = gl ? Bu1 : Bu0;
#pragma unroll
            for (int cl = 0; cl < 2; cl++) {
                int c = col0 + cp * 2 + cl;
#pragma unroll
                for (int j = 0; j < 4; j++) {
                    size_t kb = (size_t)(j * 256 + ku * 4);
                    float4 u;
                    u.x = Bu[(kb + 0) * 1024 + c];
                    u.y = Bu[(kb + 1) * 1024 + c];
                    u.z = Bu[(kb + 2) * 1024 + c];
                    u.w = Bu[(kb + 3) * 1024 + c];
                    ur[gl][cl][j] = u;
                }
            }
        }
    }

    // owners: wave0 lanes o<32: b_o=o>>2 (0..7), c_o=o&3
    if (tid < 32) {
        for (int p = 0; p < 4; p++)
            csh[p][tid] = cstate[(size_t)(p * 8 + (tid >> 2)) * 1024 + col0 + (tid & 3)];
    }

    int* gml = &bar[BAR_REL + (blockIdx.x & 15) * 64];
    int rv = AL(gml);                  // prologue: compiler load (full wait ok)
    float4 gA[8], gB[8];
    float xgA[4], xgB[4];

#define STAGE(g, xg, Qv)                                                      \
    if ((Qv) < 128) {                                                         \
        int need_ = t0 * 4 + (Qv) - 3;                                        \
        if (rv < need_) {      /* rare: genuinely at the window edge */       \
            int s_;                                                           \
            for (;;) { s_ = AL(gml); if (s_ >= need_) break;                  \
                       __builtin_amdgcn_s_sleep(1); }                         \
            rv = s_;                                                          \
        }                                                                     \
        const float* hb_ = hbuf + (size_t)(((Qv) >> 2) & 1) * 32768           \
                         + (size_t)(((Qv) & 3) * 8) * 1024;                   \
        _Pragma("unroll")                                                     \
        for (int q = 0; q < 8; q++) {                                         \
            int idx = tid + q * 256;                                          \
            const float* p_ = hb_ + (size_t)(idx >> 8) * 1024 + (idx & 255) * 4; \
            GLOAD4(g[q], p_);                                                 \
        }                                                                     \
        if (tid < 32) {   /* owners: xg for (batch=p*8+(o>>2), col=col0+(o&3)) */ \
            const float* xr = xpc + (size_t)((((Qv) >> 2) * 32) + ((Qv) & 3) * 8 \
                            + (tid >> 2)) * 4096 + col0 + (tid & 3);          \
            GLOADF(xg[0], xr);                                                \
            GLOADF(xg[1], xr + 1024);                                         \
            GLOADF(xg[2], xr + 2048);                                         \
            GLOADF(xg[3], xr + 3072);                                         \
        }                                                                     \
        GLOADI(rv, gml);       /* async refresh (stale value = safe lower bound) */ \
    }

// COMMIT(g,Qv,N0,N1): counted wait (N0 wave0 / N1 waves1-3), lagged publish,
// write LDS tile, barrier.
#define COMMIT(g, Qv, N0, N1)                                                 \
    {                                                                         \
        if (tid < 64) { WAIT_VMN(N0); } else { WAIT_VMN(N1); }                \
        if ((Qv) >= 2 && tid == 0)                                            \
            AS(&bar[blockIdx.x * 16], t0 * 4 + (Qv) - 1);                     \
        _Pragma("unroll")                                                     \
        for (int q = 0; q < 8; q++) {                                         \
            int idx = tid + q * 256;                                          \
            *(float4*)&hsh[(Qv) & 1][idx >> 8][(idx & 255) * 4] = g[q];       \
        }                                                                     \
        BARRIER_LDS();                                                        \
    }

#define PASS(Qv, xg)                                                          \
    {                                                                         \
        int tt_ = (Qv) >> 2, p_ = (Qv) & 3;                                   \
        float w_[32];                                                         \
        _Pragma("unroll")                                                     \
        for (int v = 0; v < 32; v++) w_[v] = 0.f;                             \
        _Pragma("unroll")                                                     \
        for (int b = 0; b < 8; b++) {                                         \
            _Pragma("unroll")                                                 \
            for (int j = 0; j < 4; j++) {                                     \
                float4 hv = *(const float4*)&hsh[(Qv) & 1][b][j * 256 + ku * 4]; \
                _Pragma("unroll")                                             \
                for (int gl = 0; gl < 2; gl++)                                \
                _Pragma("unroll")                                             \
                for (int cl = 0; cl < 2; cl++) {                              \
                    float4 u = ur[gl][cl][j];                                 \
                    int v = b * 4 + gl * 2 + cl;                              \
                    w_[v] = __builtin_fmaf(hv.x, u.x, w_[v]);                 \
                    w_[v] = __builtin_fmaf(hv.y, u.y, w_[v]);                 \
                    w_[v] = __builtin_fmaf(hv.z, u.z, w_[v]);                 \
                    w_[v] = __builtin_fmaf(hv.w, u.w, w_[v]);                 \
                }                                                             \
            }                                                                 \
        }                                                                     \
        /* butterfly: cl->bit0, gl->bit1, b->bits2-4, fold bit5 */            \
        float u_[16];                                                         \
        _Pragma("unroll")                                                     \
        for (int i = 0; i < 16; i++) {                                        \
            float a = w_[2 * i], b = w_[2 * i + 1];                           \
            float x = (ku & 1) ? a : b;                                       \
            float y = __shfl_xor(x, 1, 64);                                   \
            u_[i] = ((ku & 1) ? b : a) + y;                                   \
        }                                                                     \
        float v_[8];                                                          \
        _Pragma("unroll")                                                     \
        for (int i = 0; i < 8; i++) {                                         \
            float a = u_[2 * i], b = u_[2 * i + 1];                           \
            float x = (ku & 2) ? a : b;                                       \
            float y = __shfl_xor(x, 2, 64);                                   \
            v_[i] = ((ku & 2) ? b : a) + y;                                   \
        }                                                                     \
        float s_[4];                                                          \
        _Pragma("unroll")                                                     \
        for (int i = 0; i < 4; i++) {                                         \
            float a = v_[2 * i], b = v_[2 * i + 1];                           \
            float x = (ku & 4) ? a : b;                                       \
            float y = __shfl_xor(x, 4, 64);                                   \
            s_[i] = ((ku & 4) ? b : a) + y;                                   \
        }                                                                     \
        float r_[2];                                                          \
        _Pragma("unroll")                                                     \
        for (int i = 0; i < 2; i++) {                                         \
            float a = s_[2 * i], b = s_[2 * i + 1];                           \
            float x = (ku & 8) ? a : b;                                       \
            float y = __shfl_xor(x, 8, 64);                                   \
            r_[i] = ((ku & 8) ? b : a) + y;                                   \
        }                                                                     \
        float q_;                                                             \
        {                                                                     \
            float a = r_[0], b = r_[1];                                       \
            float x = (ku & 16) ? a : b;                                      \
            float y = __shfl_xor(x, 16, 64);                                  \
            q_ = ((ku & 16) ? b : a) + y;                                     \
        }                                                                     \
        q_ += __shfl_xor(q_, 32, 64);                                         \
        /* lane l<32 holds z for (cl=l&1, gl=(l>>1)&1, b=(l>>2)&7) */         \
        if (ku < 32)                                                          \
            zfin[(Qv) & 1][((ku >> 2) & 7) * 16 + (gp * 2 + ((ku >> 1) & 1)) * 4 \
                           + cp * 2 + (ku & 1)] = q_;                         \
        BARRIER_LDS();                                                        \
        if (tid < 32) {        /* owners: b_o=tid>>2, c_o=tid&3 */            \
            int b8 = (tid >> 2) * 16, c4 = tid & 3;                           \
            float zi = zfin[(Qv) & 1][b8 + 0 + c4] + xg[0];                   \
            float zf = zfin[(Qv) & 1][b8 + 4 + c4] + xg[1];                   \
            float zg = zfin[(Qv) & 1][b8 + 8 + c4] + xg[2];                   \
            float zc = zfin[(Qv) & 1][b8 + 12 + c4] + xg[3];                  \
            float ig = sigmoidf_(zi);                                         \
            float fg = sigmoidf_(zf);                                         \
            float gg = sigmoidf_(zg);   /* reference: sigmoid on g */         \
            float ct = tanhf_(zc);                                            \
            float cv = fg * csh[p_][tid] + ig * ct;                           \
            csh[p_][tid] = cv;                                                \
            float hv2 = gg * tanhf_(cv);                                      \
            int t_ = t0 + tt_;                                                \
            int bg_ = p_ * 8 + (tid >> 2);                                    \
            AS(&hbuf[(size_t)((t_ + 1) & 1) * 32768 + (size_t)bg_ * 1024      \
                     + col0 + c4], hv2);                                      \
            states[((size_t)t_ * 32 + bg_) * 1024 + col0 + c4] = hv2;         \
        }                                                                     \
    }

    // prologue: stage 0,1; counted commits (R6-verified schedule)
    STAGE(gA, xgA, 0)
    STAGE(gB, xgB, 1)
    COMMIT(gA, 0, 13, 9) PASS(0, xgA) STAGE(gA, xgA, 2)
    COMMIT(gB, 1, 15, 9) PASS(1, xgB) STAGE(gB, xgB, 3)
    COMMIT(gA, 2, 15, 9) PASS(2, xgA) STAGE(gA, xgA, 4)
    COMMIT(gB, 3, 16, 9) PASS(3, xgB) STAGE(gB, xgB, 5)

#pragma unroll 1
    for (int Q = 4; Q < 126; Q += 2) {
        COMMIT(gA, Q, 16, 9)
        PASS(Q, xgA)
        STAGE(gA, xgA, Q + 2)
        COMMIT(gB, Q + 1, 16, 9)
        PASS(Q + 1, xgB)
        STAGE(gB, xgB, Q + 3)
    }

    // final pair: no further stages -> conservative full drain on last
    COMMIT(gA, 126, 16, 9) PASS(126, xgA)
    COMMIT(gB, 127, 0, 0)  PASS(127, xgB)

    // epilogue: full drain, publish chunk completion
    WAIT_VMN(0);
    if (tid == 0) AS(&bar[blockIdx.x * 16], t0 * 4 + 128);

    // persist c-state (plain; kernel-end flush)
    if (tid < 32) {
        for (int p = 0; p < 4; p++)
            cstate[(size_t)(p * 8 + (tid >> 2)) * 1024 + col0 + (tid & 3)] = csh[p][tid];
    }
#undef STAGE
#undef COMMIT
#undef PASS
}

// ---------------------------------------------------------------------------
// gemm1: out[b][t][:] = relu(states[t*32+b][:] @ Wo + bo)  (unchanged, green)
// ---------------------------------------------------------------------------
__global__ __launch_bounds__(256) void k_gemm1(
    const float* __restrict__ A, const float* __restrict__ Wo,
    const float* __restrict__ bo, float* __restrict__ outp)
{
    __shared__ float Ash[16 * 128];
    __shared__ float Bsh[16 * 128];
    int tid = threadIdx.x;
    int bm = blockIdx.x >> 3, bn = blockIdx.x & 7;
    int r0 = bm * 128, n0 = bn * 128;
    int mg = tid >> 4, ng = tid & 15;
    int m0 = mg * 8, n0l = ng * 8;
    int sm = tid >> 1, skh = (tid & 1) * 8;
    int sk = tid >> 4, snof = (tid & 15) * 8;
    const float* aptr = A + (size_t)(r0 + sm) * 1024 + skh;

    float acc[8][8];
    for (int i = 0; i < 8; i++)
        for (int j = 0; j < 8; j++) acc[i][j] = 0.f;

    for (int k0 = 0; k0 < 1024; k0 += 16) {
        float4 av0 = *(const float4*)(aptr + k0);
        float4 av1 = *(const float4*)(aptr + k0 + 4);
        float4 bv0 = *(const float4*)(Wo + (size_t)(k0 + sk) * 1024 + n0 + snof);
        float4 bv1 = *(const float4*)(Wo + (size_t)(k0 + sk) * 1024 + n0 + snof + 4);
        Ash[(skh + 0) * 128 + sm] = av0.x;
        Ash[(skh + 1) * 128 + sm] = av0.y;
        Ash[(skh + 2) * 128 + sm] = av0.z;
        Ash[(skh + 3) * 128 + sm] = av0.w;
        Ash[(skh + 4) * 128 + sm] = av1.x;
        Ash[(skh + 5) * 128 + sm] = av1.y;
        Ash[(skh + 6) * 128 + sm] = av1.z;
        Ash[(skh + 7) * 128 + sm] = av1.w;
        *(float4*)&Bsh[sk * 128 + snof] = bv0;
        *(float4*)&Bsh[sk * 128 + snof + 4] = bv1;
        __syncthreads();
#pragma unroll
        for (int k = 0; k < 16; k++) {
            float4 a0 = *(const float4*)&Ash[k * 128 + m0];
            float4 a1 = *(const float4*)&Ash[k * 128 + m0 + 4];
            float4 b0 = *(const float4*)&Bsh[k * 128 + n0l];
            float4 b1 = *(const float4*)&Bsh[k * 128 + n0l + 4];
            float aa[8], bb[8];
            aa[0] = a0.x; aa[1] = a0.y; aa[2] = a0.z; aa[3] = a0.w;
            aa[4] = a1.x; aa[5] = a1.y; aa[6] = a1.z; aa[7] = a1.w;
            bb[0] = b0.x; bb[1] = b0.y; bb[2] = b0.z; bb[3] = b0.w;
            bb[4] = b1.x; bb[5] = b1.y; bb[6] = b1.z; bb[7] = b1.w;
#pragma unroll
            for (int i = 0; i < 8; i++)
#pragma unroll
                for (int j = 0; j < 8; j++)
                    acc[i][j] = __builtin_fmaf(aa[i], bb[j], acc[i][j]);
        }
        __syncthreads();
    }
    float fbs[8];
#pragma unroll
    for (int j = 0; j < 8; j++) fbs[j] = bo[n0 + n0l + j];
    for (int i = 0; i < 8; i++) {
        int R = r0 + m0 + i;
        size_t rowoff = (size_t)(R & 31) * 524288 + (size_t)(R >> 5) * 1024 + n0 + n0l;
#pragma unroll
        for (int j = 0; j < 8; j++) {
            float v = acc[i][j] + fbs[j];
            outp[rowoff + j] = v > 0.f ? v : 0.f;
        }
    }
}

extern "C" void kernel_launch(void* const* d_in, const int* in_sizes, int n_in,
                              void* d_out, int out_size, void* d_ws, size_t ws_size,
                              hipStream_t stream)
{
    const float* x   = (const float*)d_in[0];
    const float* Wi  = (const float*)d_in[1];
    const float* Ui  = (const float*)d_in[2];
    const float* Wf  = (const float*)d_in[3];
    const float* Uf  = (const float*)d_in[4];
    const float* Wg  = (const float*)d_in[5];
    const float* Ug  = (const float*)d_in[6];
    const float* Wc  = (const float*)d_in[7];
    const float* Uc  = (const float*)d_in[8];
    const float* Wo  = (const float*)d_in[9];
    const float* bi  = (const float*)d_in[10];
    const float* bfv = (const float*)d_in[11];
    const float* bg  = (const float*)d_in[12];
    const float* bc  = (const float*)d_in[13];
    const float* bo  = (const float*)d_in[14];

    float* ws     = (float*)d_ws;
    float* hbuf   = ws + OFF_H;
    float* cstate = ws + OFF_C;
    int*   bar    = (int*)(ws + OFF_BAR);
    float* xpc    = ws + OFF_XPC;
    float* states = ws + OFF_STATES;
    float* outp   = (float*)d_out;

    k_init<<<256, 256, 0, stream>>>(hbuf, cstate, bar);
    for (int c = 0; c < 16; c++) {
        k_gemm0<<<256, 256, 0, stream>>>(x, Wi, Wf, Wg, Wc, bi, bfv, bg, bc,
                                         xpc, c * 32);
        k_scan32<<<257, 256, 0, stream>>>(Ui, Uf, Ug, Uc, xpc,
                                          hbuf, cstate, states, bar, c * 32);
    }
    k_gemm1<<<1024, 256, 0, stream>>>(states, Wo, bo, outp);
}